// Round 11
// baseline (1805.012 us; speedup 1.0000x reference)
//
#include <hip/hip_runtime.h>
#include <hip/hip_bf16.h>
#include <math.h>

// ---- problem constants ----
#define BB 8
#define SS 512
#define EE 512
#define HH 8
#define DH 64
#define AA 32
#define OBSD 128
#define NAq 8
#define MM (BB*SS)   // 4096 token rows

typedef __bf16 v8bf __attribute__((ext_vector_type(8)));
typedef float  v4f  __attribute__((ext_vector_type(4)));

__device__ inline float gelu_f(float x) {
    float x3 = x * x * x;
    return 0.5f * x * (1.0f + tanhf(0.7978845608028654f * (x + 0.044715f * x3)));
}
__device__ inline float silu_f(float x) { return x / (1.0f + expf(-x)); }

// ---------------- seg (verified) ----------------
__global__ void seg_kernel(const int* __restrict__ dones, int* __restrict__ seg)
{
    int b = threadIdx.x;
    if (b < BB) {
        int acc = 0;
        for (int s = 0; s < SS; ++s) {
            seg[b * SS + s] = acc;
            acc += (dones[b * SS + s] != 0) ? 1 : 0;
        }
    }
}

// ---------------- fp32 -> bf16 hi/lo planes ----------------
__global__ __launch_bounds__(256)
void split_kernel(const float* __restrict__ in, __bf16* __restrict__ h,
                  __bf16* __restrict__ l, int n)
{
    int i = blockIdx.x * 256 + threadIdx.x;
    if (i < n) {
        float v = in[i];
        __bf16 hh = (__bf16)v;
        h[i] = hh;
        l[i] = (__bf16)(v - (float)hh);
    }
}

// ---------- W [K][N] fp32 -> per-matrix packed W^T hi/lo bf16 planes [N][K] ----------
// out per-matrix stride = 2*K*N bf16 (hi plane then lo plane). Same split math as
// gemm_sp_body2's in-kernel split -> identical bf16 values, just precomputed.
__global__ __launch_bounds__(256)
void wsplit_t(const float* __restrict__ W, __bf16* __restrict__ out, int K, int N)
{
    __shared__ float tile[64][65];
    const int t = threadIdx.x;
    const size_t KN = (size_t)K * N;
    const float* Wm = W + (size_t)blockIdx.z * KN;
    __bf16* oh = out + (size_t)blockIdx.z * 2 * KN;
    __bf16* ol = oh + KN;
    const int k0 = blockIdx.y * 64, n0 = blockIdx.x * 64;
    const int r = t >> 2, c0 = (t & 3) * 16;
#pragma unroll
    for (int j = 0; j < 16; j += 4) {
        float4 v = {0.f, 0.f, 0.f, 0.f};
        if (n0 + c0 + j < N)
            v = *(const float4*)&Wm[(size_t)(k0 + r) * N + n0 + c0 + j];
        *(float4*)&tile[r][c0 + j] = v;
    }
    __syncthreads();
    const int n = t >> 2, kc0 = (t & 3) * 16;
    if (n0 + n < N) {
        v8bf hv0, lv0, hv1, lv1;
#pragma unroll
        for (int j = 0; j < 8; ++j) {
            float v = tile[kc0 + j][n];
            __bf16 h = (__bf16)v; hv0[j] = h; lv0[j] = (__bf16)(v - (float)h);
            float v2 = tile[kc0 + 8 + j][n];
            __bf16 h2 = (__bf16)v2; hv1[j] = h2; lv1[j] = (__bf16)(v2 - (float)h2);
        }
        *(v8bf*)&oh[(size_t)(n0 + n) * K + k0 + kc0]     = hv0;
        *(v8bf*)&oh[(size_t)(n0 + n) * K + k0 + kc0 + 8] = hv1;
        *(v8bf*)&ol[(size_t)(n0 + n) * K + k0 + kc0]     = lv0;
        *(v8bf*)&ol[(size_t)(n0 + n) * K + k0 + kc0 + 8] = lv1;
    }
}

// ======== split-bf16 MFMA GEMM, v2 geometry (round-10 verified, FALLBACK path) ========
__device__ inline void gemm_sp_body2(const __bf16* __restrict__ Ah, const __bf16* __restrict__ Al,
                                     const float* __restrict__ W, float* __restrict__ C,
                                     int N, int K, int n0, int m0)
{
    __shared__ __bf16 Ash[128][72], Asl[128][72];   // 36.9 KB
    __shared__ __bf16 Wsh[64][72],  Wsl[64][72];    // 18.4 KB
    const int t = threadIdx.x;
    const int wv = t >> 6, lane = t & 63, quad = lane >> 4, l16 = lane & 15;
    v4f acc[2][4];
#pragma unroll
    for (int rb = 0; rb < 2; ++rb)
#pragma unroll
        for (int ct = 0; ct < 4; ++ct) acc[rb][ct] = v4f{0.f, 0.f, 0.f, 0.f};

    const int ar = t >> 1, ac0 = (t & 1) * 32;
    const int wn = t & 63, kw0 = (t >> 6) * 16;

    for (int k0 = 0; k0 < K; k0 += 64) {
#pragma unroll
        for (int i = 0; i < 4; ++i) {
            *(v8bf*)&Ash[ar][ac0 + 8 * i] = *(const v8bf*)&Ah[(size_t)(m0 + ar) * K + k0 + ac0 + 8 * i];
            *(v8bf*)&Asl[ar][ac0 + 8 * i] = *(const v8bf*)&Al[(size_t)(m0 + ar) * K + k0 + ac0 + 8 * i];
        }
        {
            const int gn = n0 + wn;
            v8bf h0, l0, h1, l1;
            if (gn < N) {
#pragma unroll
                for (int j = 0; j < 8; ++j) {
                    float w = W[(size_t)(k0 + kw0 + j) * N + gn];
                    h0[j] = (__bf16)w;  l0[j] = (__bf16)(w - (float)h0[j]);
                    float w2 = W[(size_t)(k0 + kw0 + 8 + j) * N + gn];
                    h1[j] = (__bf16)w2; l1[j] = (__bf16)(w2 - (float)h1[j]);
                }
            } else {
#pragma unroll
                for (int j = 0; j < 8; ++j) {
                    h0[j] = (__bf16)0.0f; l0[j] = (__bf16)0.0f;
                    h1[j] = (__bf16)0.0f; l1[j] = (__bf16)0.0f;
                }
            }
            *(v8bf*)&Wsh[wn][kw0]     = h0;  *(v8bf*)&Wsl[wn][kw0]     = l0;
            *(v8bf*)&Wsh[wn][kw0 + 8] = h1;  *(v8bf*)&Wsl[wn][kw0 + 8] = l1;
        }
        __syncthreads();
#pragma unroll
        for (int kk = 0; kk < 2; ++kk) {
            v8bf ah0 = *(const v8bf*)&Ash[wv * 32 + l16][kk * 32 + quad * 8];
            v8bf al0 = *(const v8bf*)&Asl[wv * 32 + l16][kk * 32 + quad * 8];
            v8bf ah1 = *(const v8bf*)&Ash[wv * 32 + 16 + l16][kk * 32 + quad * 8];
            v8bf al1 = *(const v8bf*)&Asl[wv * 32 + 16 + l16][kk * 32 + quad * 8];
#pragma unroll
            for (int ct = 0; ct < 4; ++ct) {
                v8bf bh = *(const v8bf*)&Wsh[ct * 16 + l16][kk * 32 + quad * 8];
                v8bf bl = *(const v8bf*)&Wsl[ct * 16 + l16][kk * 32 + quad * 8];
                acc[0][ct] = __builtin_amdgcn_mfma_f32_16x16x32_bf16(ah0, bh, acc[0][ct], 0, 0, 0);
                acc[0][ct] = __builtin_amdgcn_mfma_f32_16x16x32_bf16(ah0, bl, acc[0][ct], 0, 0, 0);
                acc[0][ct] = __builtin_amdgcn_mfma_f32_16x16x32_bf16(al0, bh, acc[0][ct], 0, 0, 0);
                acc[1][ct] = __builtin_amdgcn_mfma_f32_16x16x32_bf16(ah1, bh, acc[1][ct], 0, 0, 0);
                acc[1][ct] = __builtin_amdgcn_mfma_f32_16x16x32_bf16(ah1, bl, acc[1][ct], 0, 0, 0);
                acc[1][ct] = __builtin_amdgcn_mfma_f32_16x16x32_bf16(al1, bh, acc[1][ct], 0, 0, 0);
            }
        }
        __syncthreads();
    }
#pragma unroll
    for (int rb = 0; rb < 2; ++rb)
#pragma unroll
        for (int ct = 0; ct < 4; ++ct) {
            int gn = n0 + ct * 16 + l16;
            if (gn < N) {
#pragma unroll
                for (int r = 0; r < 4; ++r)
                    C[(size_t)(m0 + wv * 32 + rb * 16 + quad * 4 + r) * N + gn] = acc[rb][ct][r];
            }
        }
}

__global__ __launch_bounds__(256)
void gemm_sp(const __bf16* __restrict__ Ah, const __bf16* __restrict__ Al,
             const float* __restrict__ W, float* __restrict__ C, int N, int K)
{
    gemm_sp_body2(Ah, Al, W, C, N, K, blockIdx.x * 64, blockIdx.y * 128);
}

__global__ __launch_bounds__(256)
void gemm_sp_multi(const __bf16* __restrict__ A0h, const __bf16* __restrict__ A0l,
                   const __bf16* __restrict__ A1h, const __bf16* __restrict__ A1l,
                   int selA, const float* __restrict__ W, float* __restrict__ C)
{
    const int g = blockIdx.x >> 3;
    const int n0 = (blockIdx.x & 7) * 64;
    const int s = (selA >> g) & 1;
    const __bf16* Ah = s ? A1h : A0h;
    const __bf16* Al = s ? A1l : A0l;
    gemm_sp_body2(Ah, Al, W + (size_t)g * EE * EE, C + (size_t)g * (size_t)MM * EE,
                  EE, EE, n0, blockIdx.y * 128);
}

// ======== pre-split GEMM: W^T hi/lo planes read directly from global (L2-hot) ========
// Same fragment math and MFMA order as gemm_sp_body2; W staging removed entirely ->
// LDS 36.9 KB (4 blocks/CU) and no per-tile fp32 split VALU.
__device__ inline void gemm_ps_body(const __bf16* __restrict__ Ah, const __bf16* __restrict__ Al,
                                    const __bf16* __restrict__ Wth, const __bf16* __restrict__ Wtl,
                                    float* __restrict__ C, int N, int K, int n0, int m0)
{
    __shared__ __bf16 Ash[128][72], Asl[128][72];   // 36.9 KB
    const int t = threadIdx.x;
    const int wv = t >> 6, lane = t & 63, quad = lane >> 4, l16 = lane & 15;
    v4f acc[2][4];
#pragma unroll
    for (int rb = 0; rb < 2; ++rb)
#pragma unroll
        for (int ct = 0; ct < 4; ++ct) acc[rb][ct] = v4f{0.f, 0.f, 0.f, 0.f};

    const int ar = t >> 1, ac0 = (t & 1) * 32;

    for (int k0 = 0; k0 < K; k0 += 64) {
#pragma unroll
        for (int i = 0; i < 4; ++i) {
            *(v8bf*)&Ash[ar][ac0 + 8 * i] = *(const v8bf*)&Ah[(size_t)(m0 + ar) * K + k0 + ac0 + 8 * i];
            *(v8bf*)&Asl[ar][ac0 + 8 * i] = *(const v8bf*)&Al[(size_t)(m0 + ar) * K + k0 + ac0 + 8 * i];
        }
        __syncthreads();
#pragma unroll
        for (int kk = 0; kk < 2; ++kk) {
            v8bf ah0 = *(const v8bf*)&Ash[wv * 32 + l16][kk * 32 + quad * 8];
            v8bf al0 = *(const v8bf*)&Asl[wv * 32 + l16][kk * 32 + quad * 8];
            v8bf ah1 = *(const v8bf*)&Ash[wv * 32 + 16 + l16][kk * 32 + quad * 8];
            v8bf al1 = *(const v8bf*)&Asl[wv * 32 + 16 + l16][kk * 32 + quad * 8];
#pragma unroll
            for (int ct = 0; ct < 4; ++ct) {
                const int gn = n0 + ct * 16 + l16;
                v8bf bh, bl;
                if (gn < N) {
                    const size_t wb = (size_t)gn * K + k0 + kk * 32 + quad * 8;
                    bh = *(const v8bf*)&Wth[wb];
                    bl = *(const v8bf*)&Wtl[wb];
                } else {
#pragma unroll
                    for (int j = 0; j < 8; ++j) { bh[j] = (__bf16)0.0f; bl[j] = (__bf16)0.0f; }
                }
                acc[0][ct] = __builtin_amdgcn_mfma_f32_16x16x32_bf16(ah0, bh, acc[0][ct], 0, 0, 0);
                acc[0][ct] = __builtin_amdgcn_mfma_f32_16x16x32_bf16(ah0, bl, acc[0][ct], 0, 0, 0);
                acc[0][ct] = __builtin_amdgcn_mfma_f32_16x16x32_bf16(al0, bh, acc[0][ct], 0, 0, 0);
                acc[1][ct] = __builtin_amdgcn_mfma_f32_16x16x32_bf16(ah1, bh, acc[1][ct], 0, 0, 0);
                acc[1][ct] = __builtin_amdgcn_mfma_f32_16x16x32_bf16(ah1, bl, acc[1][ct], 0, 0, 0);
                acc[1][ct] = __builtin_amdgcn_mfma_f32_16x16x32_bf16(al1, bh, acc[1][ct], 0, 0, 0);
            }
        }
        __syncthreads();
    }
#pragma unroll
    for (int rb = 0; rb < 2; ++rb)
#pragma unroll
        for (int ct = 0; ct < 4; ++ct) {
            int gn = n0 + ct * 16 + l16;
            if (gn < N) {
#pragma unroll
                for (int r = 0; r < 4; ++r)
                    C[(size_t)(m0 + wv * 32 + rb * 16 + quad * 4 + r) * N + gn] = acc[rb][ct][r];
            }
        }
}

__global__ __launch_bounds__(256)
void gemm_ps(const __bf16* __restrict__ Ah, const __bf16* __restrict__ Al,
             const __bf16* __restrict__ Wt, float* __restrict__ C, int N, int K)
{
    gemm_ps_body(Ah, Al, Wt, Wt + (size_t)K * N, C, N, K, blockIdx.x * 64, blockIdx.y * 128);
}

__global__ __launch_bounds__(256)
void gemm_ps_multi(const __bf16* __restrict__ A0h, const __bf16* __restrict__ A0l,
                   const __bf16* __restrict__ A1h, const __bf16* __restrict__ A1l,
                   int selA, const __bf16* __restrict__ Wt, float* __restrict__ C)
{
    const int g = blockIdx.x >> 3;
    const int n0 = (blockIdx.x & 7) * 64;
    const int s = (selA >> g) & 1;
    const __bf16* Ah = s ? A1h : A0h;
    const __bf16* Al = s ? A1l : A0l;
    const __bf16* Wth = Wt + (size_t)g * 2 * EE * EE;
    gemm_ps_body(Ah, Al, Wth, Wth + (size_t)EE * EE,
                 C + (size_t)g * (size_t)MM * EE, EE, EE, n0, blockIdx.y * 128);
}

// ===== hybrid retention (round-10 verified PASS config, unchanged) =====
__global__ __launch_bounds__(256)
void ret_hyb2(const float* __restrict__ Q, const float* __restrict__ K,
              const float* __restrict__ V, const float* __restrict__ G,
              const int* __restrict__ seg,
              __bf16* __restrict__ oh, __bf16* __restrict__ ol, int causal)
{
    __shared__ __align__(16) __bf16 Ksh[64][72], Ks1[64][72], Ks2[64][72]; // K planes
    __shared__ __align__(16) float  Vs[64][68];                 // V [m][d] fp32
    __shared__ __align__(16) float  Ps[64][68];                 // P [n][m] fp32
    __shared__ int    segm[64];

    const int t = threadIdx.x;
    const int wv = t >> 6, lane = t & 63, q = lane >> 4, l16 = lane & 15;
    const int nt = blockIdx.x, bh = blockIdx.y;
    const int b = bh >> 3, h = bh & 7;
    const int n0 = nt * 64;
    const size_t base = ((size_t)b * SS) * EE + (size_t)h * DH;
    const float lgg = log2f(1.0f - exp2f(-5.0f - (float)h));

    const int n_a = n0 + wv * 16 + l16;
    v8bf qh[2], q1[2], q2[2];
#pragma unroll
    for (int kk = 0; kk < 2; ++kk) {
        const float* qp = &Q[base + (size_t)n_a * EE + kk * 32 + q * 8];
#pragma unroll
        for (int j = 0; j < 8; ++j) {
            float v = qp[j] * 0.125f;
            __bf16 hh = (__bf16)v;      float r1 = v - (float)hh;
            __bf16 a1 = (__bf16)r1;     float r2 = r1 - (float)a1;
            qh[kk][j] = hh;
            q1[kk][j] = a1;
            q2[kk][j] = (__bf16)r2;
        }
    }
    int nrow[4], sn_[4];
#pragma unroll
    for (int r = 0; r < 4; ++r) {
        nrow[r] = n0 + wv * 16 + q * 4 + r;
        sn_[r] = seg[b * SS + nrow[r]];
    }

    const int rp = t >> 3, dc = (t & 7) * 8;
    float o0[8], o1[8];
#pragma unroll
    for (int j = 0; j < 8; ++j) { o0[j] = 0.f; o1[j] = 0.f; }

    const int mp2 = (t >> 3) * 2;
    const int d0k = (t & 7) * 8;
    const int mr = t >> 2;
    const int c0 = (t & 3) * 16;

    const int mtmax = causal ? nt : (SS / 64 - 1);
    for (int mt = 0; mt <= mtmax; ++mt) {
        const int m0 = mt * 64;
        {
            const float* kp0 = &K[base + (size_t)(m0 + mp2) * EE + d0k];
            float k0[8], k1[8];
            *(float4*)&k0[0] = *(const float4*)&kp0[0];
            *(float4*)&k0[4] = *(const float4*)&kp0[4];
            *(float4*)&k1[0] = *(const float4*)&kp0[EE];
            *(float4*)&k1[4] = *(const float4*)&kp0[EE + 4];
            v8bf kh0, ka0, kb0, kh1, ka1, kb1;
#pragma unroll
            for (int j = 0; j < 8; ++j) {
                __bf16 hh = (__bf16)k0[j];  float r1 = k0[j] - (float)hh;
                __bf16 aa = (__bf16)r1;     float r2 = r1 - (float)aa;
                kh0[j] = hh; ka0[j] = aa; kb0[j] = (__bf16)r2;
                __bf16 hh1 = (__bf16)k1[j]; float s1_ = k1[j] - (float)hh1;
                __bf16 aa1 = (__bf16)s1_;   float s2_ = s1_ - (float)aa1;
                kh1[j] = hh1; ka1[j] = aa1; kb1[j] = (__bf16)s2_;
            }
            *(v8bf*)&Ksh[mp2][d0k]     = kh0;
            *(v8bf*)&Ks1[mp2][d0k]     = ka0;
            *(v8bf*)&Ks2[mp2][d0k]     = kb0;
            *(v8bf*)&Ksh[mp2 + 1][d0k] = kh1;
            *(v8bf*)&Ks1[mp2 + 1][d0k] = ka1;
            *(v8bf*)&Ks2[mp2 + 1][d0k] = kb1;
        }
        {
            const float* vp = &V[base + (size_t)(m0 + mr) * EE + c0];
#pragma unroll
            for (int j = 0; j < 16; j += 4)
                *(float4*)&Vs[mr][c0 + j] = *(const float4*)&vp[j];
        }
        if (t < 64) segm[t] = seg[b * SS + m0 + t];
        __syncthreads();

        v4f sacc[4];
#pragma unroll
        for (int i = 0; i < 4; ++i) sacc[i] = v4f{0.f, 0.f, 0.f, 0.f};
#pragma unroll
        for (int ct = 0; ct < 4; ++ct) {
            const int mrow = ct * 16 + l16;
#pragma unroll
            for (int kk = 0; kk < 2; ++kk) {
                v8bf bh = *(const v8bf*)&Ksh[mrow][kk * 32 + q * 8];
                v8bf b1 = *(const v8bf*)&Ks1[mrow][kk * 32 + q * 8];
                v8bf b2 = *(const v8bf*)&Ks2[mrow][kk * 32 + q * 8];
                sacc[ct] = __builtin_amdgcn_mfma_f32_16x16x32_bf16(qh[kk], bh, sacc[ct], 0, 0, 0);
                sacc[ct] = __builtin_amdgcn_mfma_f32_16x16x32_bf16(qh[kk], b1, sacc[ct], 0, 0, 0);
                sacc[ct] = __builtin_amdgcn_mfma_f32_16x16x32_bf16(q1[kk], bh, sacc[ct], 0, 0, 0);
                sacc[ct] = __builtin_amdgcn_mfma_f32_16x16x32_bf16(q1[kk], b1, sacc[ct], 0, 0, 0);
                sacc[ct] = __builtin_amdgcn_mfma_f32_16x16x32_bf16(qh[kk], b2, sacc[ct], 0, 0, 0);
                sacc[ct] = __builtin_amdgcn_mfma_f32_16x16x32_bf16(q2[kk], bh, sacc[ct], 0, 0, 0);
            }
        }

#pragma unroll
        for (int ct = 0; ct < 4; ++ct) {
            const int m_g = m0 + ct * 16 + l16;
            const int sm = segm[ct * 16 + l16];
#pragma unroll
            for (int r = 0; r < 4; ++r) {
                const int delta = nrow[r] - m_g;
                float f = 0.0f;
                if (sm == sn_[r]) {
                    if (causal) f = (delta >= 0) ? exp2f(lgg * (float)delta) : 0.0f;
                    else        f = exp2f(lgg * fabsf((float)delta));
                }
                Ps[wv * 16 + q * 4 + r][ct * 16 + l16] = sacc[ct][r] * f;
            }
        }
        __syncthreads();

        for (int m = 0; m < 64; m += 4) {
            float4 pa = *(const float4*)&Ps[2 * rp][m];
            float4 pb = *(const float4*)&Ps[2 * rp + 1][m];
#pragma unroll
            for (int j = 0; j < 8; ++j) {
                float v0 = Vs[m + 0][dc + j];
                float v1 = Vs[m + 1][dc + j];
                float v2 = Vs[m + 2][dc + j];
                float v3 = Vs[m + 3][dc + j];
                float a0 = o0[j];
                a0 += pa.x * v0; a0 += pa.y * v1; a0 += pa.z * v2; a0 += pa.w * v3;
                o0[j] = a0;
                float a1 = o1[j];
                a1 += pb.x * v0; a1 += pb.y * v1; a1 += pb.z * v2; a1 += pb.w * v3;
                o1[j] = a1;
            }
        }
        __syncthreads();
    }

    float s10 = 0.f, s20 = 0.f, s11 = 0.f, s21 = 0.f;
#pragma unroll
    for (int j = 0; j < 8; ++j) {
        s10 += o0[j]; s20 += o0[j] * o0[j];
        s11 += o1[j]; s21 += o1[j] * o1[j];
    }
#pragma unroll
    for (int mk = 1; mk < 8; mk <<= 1) {
        s10 += __shfl_xor(s10, mk); s20 += __shfl_xor(s20, mk);
        s11 += __shfl_xor(s11, mk); s21 += __shfl_xor(s21, mk);
    }
    const float mu0 = s10 * (1.0f / 64.0f);
    const float var0 = s20 * (1.0f / 64.0f) - mu0 * mu0;
    const float rstd0 = rsqrtf(var0 + 1e-6f);
    const float mu1 = s11 * (1.0f / 64.0f);
    const float var1 = s21 * (1.0f / 64.0f) - mu1 * mu1;
    const float rstd1 = rsqrtf(var1 + 1e-6f);

    const size_t ob = base + (size_t)(n0 + 2 * rp) * EE + dc;
    const float* gp0 = &G[ob];
    v8bf h0v, l0v, h1v, l1v;
#pragma unroll
    for (int j = 0; j < 8; ++j) {
        float y0 = (o0[j] - mu0) * rstd0;
        float w0 = silu_f(gp0[j]) * y0;
        __bf16 hh0 = (__bf16)w0; h0v[j] = hh0; l0v[j] = (__bf16)(w0 - (float)hh0);
        float y1 = (o1[j] - mu1) * rstd1;
        float w1 = silu_f(gp0[EE + j]) * y1;
        __bf16 hh1 = (__bf16)w1; h1v[j] = hh1; l1v[j] = (__bf16)(w1 - (float)hh1);
    }
    *(v8bf*)&oh[ob] = h0v;      *(v8bf*)&ol[ob] = l0v;
    *(v8bf*)&oh[ob + EE] = h1v; *(v8bf*)&ol[ob + EE] = l1v;
}

// ---------------- rms_fast: fp32 out + bf16 hi/lo planes (verified) ----------------
__global__ __launch_bounds__(256)
void rms_fast(const float* __restrict__ A, const float* __restrict__ Bv,
              const float* __restrict__ scale, float* __restrict__ out,
              __bf16* __restrict__ oh, __bf16* __restrict__ ol, int mode)
{
    int row = blockIdx.x, t = threadIdx.x;
    __shared__ float red[4];
    size_t base = (size_t)row * EE;
    float v0 = A[base + t], v1 = A[base + t + 256];
    if (mode == 1) { v0 += Bv[base + t]; v1 += Bv[base + t + 256]; }
    else if (mode == 2) { v0 = gelu_f(v0); v1 = gelu_f(v1); }
    float ss = v0 * v0 + v1 * v1;
#pragma unroll
    for (int mk = 32; mk; mk >>= 1) ss += __shfl_xor(ss, mk);
    if ((t & 63) == 0) red[t >> 6] = ss;
    __syncthreads();
    float tot = red[0] + red[1] + red[2] + red[3];
    float r = rsqrtf(tot * (1.0f / 512.0f) + 1e-6f);
    float o0 = v0 * r * scale[t];
    float o1 = v1 * r * scale[t + 256];
    out[base + t] = o0;
    out[base + t + 256] = o1;
    __bf16 h0 = (__bf16)o0, h1 = (__bf16)o1;
    oh[base + t] = h0;        ol[base + t] = (__bf16)(o0 - (float)h0);
    oh[base + t + 256] = h1;  ol[base + t + 256] = (__bf16)(o1 - (float)h1);
}

__global__ __launch_bounds__(256)
void smul_planes(const float* __restrict__ A, const float* __restrict__ Bv,
                 __bf16* __restrict__ oh, __bf16* __restrict__ ol)
{
    int i = blockIdx.x * 256 + threadIdx.x;
    float v = silu_f(A[i]) * Bv[i];
    __bf16 h = (__bf16)v;
    oh[i] = h;
    ol[i] = (__bf16)(v - (float)h);
}

__global__ __launch_bounds__(256)
void gather_dumb(const int* __restrict__ action, const float* __restrict__ act_w,
                 float* __restrict__ out)
{
    int idx = blockIdx.x * 256 + threadIdx.x;
    int row = idx >> 9, e = idx & 511;
    int b = row >> 9, s = row & 511;
    int id = (s % NAq == 0) ? 0 : (action[b * SS + s - 1] + 1);
    out[(size_t)row * EE + e] = act_w[(size_t)id * EE + e];
}

extern "C" void kernel_launch(void* const* d_in, const int* in_sizes, int n_in,
                              void* d_out, int out_size, void* d_ws, size_t ws_size,
                              hipStream_t stream)
{
    (void)in_sizes; (void)n_in; (void)out_size;
    const float* obs      = (const float*)d_in[0];
    const int*   action   = (const int*)d_in[1];
    const int*   dones    = (const int*)d_in[3];
    const float* obs_w    = (const float*)d_in[4];
    const float* enc_ln0  = (const float*)d_in[5];
    const float* enc_ret  = (const float*)d_in[6];
    const float* enc_ln   = (const float*)d_in[7];
    const float* enc_ffn  = (const float*)d_in[8];
    const float* act_w    = (const float*)d_in[9];
    const float* dec_ln0  = (const float*)d_in[10];
    const float* dec_ret1 = (const float*)d_in[11];
    const float* dec_ret2 = (const float*)d_in[12];
    const float* dec_ln   = (const float*)d_in[13];
    const float* dec_ffn  = (const float*)d_in[14];
    const float* head_w1  = (const float*)d_in[15];
    const float* head_ln  = (const float*)d_in[16];
    const float* head_w2  = (const float*)d_in[17];
    float* out = (float*)d_out;

    float* ws = (float*)d_ws;
    const size_t SZ = (size_t)MM * EE;
    const size_t EE2 = (size_t)EE * EE;
    const size_t M2 = 2 * EE2;          // per-matrix packed W^T stride (bf16)
    int* seg  = (int*)ws;
    float* fb = ws + 8192;
    float *x  = fb + 0 * SZ, *y  = fb + 1 * SZ, *y2 = fb + 2 * SZ;
    float *Qf = fb + 3 * SZ, *Kf = fb + 4 * SZ, *Vf = fb + 5 * SZ;
    float *Gb = fb + 6 * SZ, *Tb = fb + 7 * SZ, *Ob = fb + 8 * SZ;
    float *QKVG = Qf;
    float *FFN2 = Gb;
    __bf16* bp = (__bf16*)(fb + 9 * SZ);
    __bf16 *xh = bp + 0 * SZ, *xl = bp + 1 * SZ;
    __bf16 *yh = bp + 2 * SZ, *yl = bp + 3 * SZ;
    __bf16 *sh = bp + 4 * SZ, *sl = bp + 5 * SZ;
    __bf16 *obsh = bp + 6 * SZ, *obsl = obsh + (size_t)MM * OBSD;

    // ---- pre-split W^T plane region (after obs planes) ----
    __bf16* wt          = obsl + (size_t)MM * OBSD;
    __bf16* wt_enc_ret  = wt;
    __bf16* wt_enc_ffn  = wt_enc_ret  + 10 * M2;
    __bf16* wt_dec_ret1 = wt_enc_ffn  + 6  * M2;
    __bf16* wt_dec_ret2 = wt_dec_ret1 + 10 * M2;
    __bf16* wt_dec_ffn  = wt_dec_ret2 + 10 * M2;
    __bf16* wt_head1    = wt_dec_ffn  + 6  * M2;
    __bf16* wt_obs      = wt_head1    + M2;
    __bf16* wt_head2    = wt_obs      + 2 * (size_t)OBSD * EE;
    __bf16* wt_end      = wt_head2    + 2 * (size_t)EE * AA;
    const size_t need = (size_t)((const char*)wt_end - (const char*)ws);
    const bool pre = (ws_size >= need);

    dim3 blk(256);

    seg_kernel<<<dim3(1), dim3(64), 0, stream>>>(dones, seg);
    split_kernel<<<dim3(MM * OBSD / 256), blk, 0, stream>>>(obs, obsh, obsl, MM * OBSD);

    if (pre) {
        wsplit_t<<<dim3(8, 8, 10), blk, 0, stream>>>(enc_ret,  wt_enc_ret,  EE, EE);
        wsplit_t<<<dim3(8, 8, 6),  blk, 0, stream>>>(enc_ffn,  wt_enc_ffn,  EE, EE);
        wsplit_t<<<dim3(8, 8, 10), blk, 0, stream>>>(dec_ret1, wt_dec_ret1, EE, EE);
        wsplit_t<<<dim3(8, 8, 10), blk, 0, stream>>>(dec_ret2, wt_dec_ret2, EE, EE);
        wsplit_t<<<dim3(8, 8, 6),  blk, 0, stream>>>(dec_ffn,  wt_dec_ffn,  EE, EE);
        wsplit_t<<<dim3(8, 8, 1),  blk, 0, stream>>>(head_w1,  wt_head1,    EE, EE);
        wsplit_t<<<dim3(8, 2, 1),  blk, 0, stream>>>(obs_w,    wt_obs,      OBSD, EE);
        wsplit_t<<<dim3(1, 8, 1),  blk, 0, stream>>>(head_w2,  wt_head2,    EE, AA);
    }

    auto gemmF = [&](const __bf16* Ah, const __bf16* Al, const float* W, const __bf16* Wt,
                     float* C, int N, int K) {
        if (pre) gemm_ps<<<dim3((N + 63) / 64, MM / 128), blk, 0, stream>>>(Ah, Al, Wt, C, N, K);
        else     gemm_sp<<<dim3((N + 63) / 64, MM / 128), blk, 0, stream>>>(Ah, Al, W, C, N, K);
    };
    auto gemmM = [&](const __bf16* A0h_, const __bf16* A0l_,
                     const __bf16* A1h_, const __bf16* A1l_, int selA,
                     const float* W, const __bf16* Wt, float* C, int ng) {
        if (pre) gemm_ps_multi<<<dim3(8 * ng, MM / 128), blk, 0, stream>>>(A0h_, A0l_, A1h_, A1l_, selA, Wt, C);
        else     gemm_sp_multi<<<dim3(8 * ng, MM / 128), blk, 0, stream>>>(A0h_, A0l_, A1h_, A1l_, selA, W, C);
    };
    auto rms = [&](const float* A, const float* Bv, const float* sc,
                   float* o, __bf16* oh, __bf16* ol, int mode) {
        rms_fast<<<dim3(MM), blk, 0, stream>>>(A, Bv, sc, o, oh, ol, mode);
    };
    auto smul = [&](const float* A, const float* Bv, __bf16* oh, __bf16* ol) {
        smul_planes<<<dim3((int)(SZ / 256)), blk, 0, stream>>>(A, Bv, oh, ol);
    };
    auto attn = [&](int causal) {
        ret_hyb2<<<dim3(SS / 64, BB * HH), blk, 0, stream>>>(Qf, Kf, Vf, Gb, seg, sh, sl, causal);
    };

    // ---- encoder ----
    gemmF(obsh, obsl, obs_w, wt_obs, Ob, EE, OBSD);
    rms(Ob, nullptr, enc_ln0, x, xh, xl, 2);
    for (int i = 0; i < 2; ++i) {
        const float* r = enc_ret + (size_t)i * 5 * EE2;
        const __bf16* rt = wt_enc_ret + (size_t)i * 5 * M2;
        gemmM(xh, xl, xh, xl, 0, r, rt, QKVG, 4);     // Q,K,V,G <- x
        attn(0);                                      // full D_f -> sh/sl (gated)
        gemmF(sh, sl, r + 4 * EE2, rt + 4 * M2, Ob, EE, EE);
        rms(x, Ob, enc_ln + (size_t)(i * 2 + 0) * EE, x, xh, xl, 1);
        const float* f = enc_ffn + (size_t)i * 3 * EE2;
        const __bf16* ft = wt_enc_ffn + (size_t)i * 3 * M2;
        gemmM(xh, xl, xh, xl, 0, f, ft, FFN2, 2);     // gate,up <- x  (Gb,Tb)
        smul(Gb, Tb, sh, sl);
        gemmF(sh, sl, f + 2 * EE2, ft + 2 * M2, Ob, EE, EE);
        rms(x, Ob, enc_ln + (size_t)(i * 2 + 1) * EE, x, xh, xl, 1);
    }

    // ---- decoder ----
    gather_dumb<<<dim3((int)(SZ / 256)), blk, 0, stream>>>(action, act_w, Ob);
    rms(Ob, nullptr, dec_ln0, y, yh, yl, 2);
    for (int i = 0; i < 2; ++i) {
        const float* r1 = dec_ret1 + (size_t)i * 5 * EE2;
        const __bf16* r1t = wt_dec_ret1 + (size_t)i * 5 * M2;
        gemmM(yh, yl, yh, yl, 0, r1, r1t, QKVG, 4);   // all <- y
        attn(1);                                      // causal D_c -> sh/sl (gated)
        gemmF(sh, sl, r1 + 4 * EE2, r1t + 4 * M2, Ob, EE, EE);
        rms(y, Ob, dec_ln + (size_t)(i * 3 + 0) * EE, y, yh, yl, 1);

        const float* r2 = dec_ret2 + (size_t)i * 5 * EE2;
        const __bf16* r2t = wt_dec_ret2 + (size_t)i * 5 * M2;
        gemmM(xh, xl, yh, yl, 0b0110, r2, r2t, QKVG, 4);  // Q<-x, K<-y, V<-y, G<-x
        attn(1);
        gemmF(sh, sl, r2 + 4 * EE2, r2t + 4 * M2, Ob, EE, EE);
        rms(x, Ob, dec_ln + (size_t)(i * 3 + 1) * EE, y2, sh, sl, 1);   // y2 planes = sh/sl

        const float* f = dec_ffn + (size_t)i * 3 * EE2;
        const __bf16* ft = wt_dec_ffn + (size_t)i * 3 * M2;
        gemmM(sh, sl, sh, sl, 0, f, ft, FFN2, 2);     // gate,up <- y2
        smul(Gb, Tb, sh, sl);
        gemmF(sh, sl, f + 2 * EE2, ft + 2 * M2, Ob, EE, EE);
        rms(y2, Ob, dec_ln + (size_t)(i * 3 + 2) * EE, y, yh, yl, 1);
    }

    // ---- head ----
    gemmF(yh, yl, head_w1, wt_head1, Ob, EE, EE);
    rms(Ob, nullptr, head_ln, Tb, sh, sl, 2);
    gemmF(sh, sl, head_w2, wt_head2, out, AA, EE);
}

// Round 14
// 1278.500 us; speedup vs baseline: 1.4118x; 1.4118x over previous
//
#include <hip/hip_runtime.h>
#include <hip/hip_bf16.h>
#include <math.h>

// ---- problem constants ----
#define BB 8
#define SS 512
#define EE 512
#define HH 8
#define DH 64
#define AA 32
#define OBSD 128
#define NAq 8
#define MM (BB*SS)   // 4096 token rows

typedef __bf16 v8bf __attribute__((ext_vector_type(8)));
typedef float  v4f  __attribute__((ext_vector_type(4)));

__device__ inline float gelu_f(float x) {
    float x3 = x * x * x;
    return 0.5f * x * (1.0f + tanhf(0.7978845608028654f * (x + 0.044715f * x3)));
}
__device__ inline float silu_f(float x) { return x / (1.0f + expf(-x)); }

// ---------------- seg (verified) ----------------
__global__ void seg_kernel(const int* __restrict__ dones, int* __restrict__ seg)
{
    int b = threadIdx.x;
    if (b < BB) {
        int acc = 0;
        for (int s = 0; s < SS; ++s) {
            seg[b * SS + s] = acc;
            acc += (dones[b * SS + s] != 0) ? 1 : 0;
        }
    }
}

// ---------------- fp32 -> bf16 hi/lo planes ----------------
__global__ __launch_bounds__(256)
void split_kernel(const float* __restrict__ in, __bf16* __restrict__ h,
                  __bf16* __restrict__ l, int n)
{
    int i = blockIdx.x * 256 + threadIdx.x;
    if (i < n) {
        float v = in[i];
        __bf16 hh = (__bf16)v;
        h[i] = hh;
        l[i] = (__bf16)(v - (float)hh);
    }
}

// ---------- W [K][N] fp32 -> per-matrix packed W^T hi/lo bf16 planes [N][K] ----------
// (round-11 verified: full pipeline passed with these values)
__global__ __launch_bounds__(256)
void wsplit_t(const float* __restrict__ W, __bf16* __restrict__ out, int K, int N)
{
    __shared__ float tile[64][65];
    const int t = threadIdx.x;
    const size_t KN = (size_t)K * N;
    const float* Wm = W + (size_t)blockIdx.z * KN;
    __bf16* oh = out + (size_t)blockIdx.z * 2 * KN;
    __bf16* ol = oh + KN;
    const int k0 = blockIdx.y * 64, n0 = blockIdx.x * 64;
    const int r = t >> 2, c0 = (t & 3) * 16;
#pragma unroll
    for (int j = 0; j < 16; j += 4) {
        float4 v = {0.f, 0.f, 0.f, 0.f};
        if (n0 + c0 + j < N)
            v = *(const float4*)&Wm[(size_t)(k0 + r) * N + n0 + c0 + j];
        *(float4*)&tile[r][c0 + j] = v;
    }
    __syncthreads();
    const int n = t >> 2, kc0 = (t & 3) * 16;
    if (n0 + n < N) {
        v8bf hv0, lv0, hv1, lv1;
#pragma unroll
        for (int j = 0; j < 8; ++j) {
            float v = tile[kc0 + j][n];
            __bf16 h = (__bf16)v; hv0[j] = h; lv0[j] = (__bf16)(v - (float)h);
            float v2 = tile[kc0 + 8 + j][n];
            __bf16 h2 = (__bf16)v2; hv1[j] = h2; lv1[j] = (__bf16)(v2 - (float)h2);
        }
        *(v8bf*)&oh[(size_t)(n0 + n) * K + k0 + kc0]     = hv0;
        *(v8bf*)&oh[(size_t)(n0 + n) * K + k0 + kc0 + 8] = hv1;
        *(v8bf*)&ol[(size_t)(n0 + n) * K + k0 + kc0]     = lv0;
        *(v8bf*)&ol[(size_t)(n0 + n) * K + k0 + kc0 + 8] = lv1;
    }
}

// ======== split-bf16 MFMA GEMM, v2 geometry (round-10 verified, FALLBACK path) ========
__device__ inline void gemm_sp_body2(const __bf16* __restrict__ Ah, const __bf16* __restrict__ Al,
                                     const float* __restrict__ W, float* __restrict__ C,
                                     int N, int K, int n0, int m0)
{
    __shared__ __bf16 Ash[128][72], Asl[128][72];   // 36.9 KB
    __shared__ __bf16 Wsh[64][72],  Wsl[64][72];    // 18.4 KB
    const int t = threadIdx.x;
    const int wv = t >> 6, lane = t & 63, quad = lane >> 4, l16 = lane & 15;
    v4f acc[2][4];
#pragma unroll
    for (int rb = 0; rb < 2; ++rb)
#pragma unroll
        for (int ct = 0; ct < 4; ++ct) acc[rb][ct] = v4f{0.f, 0.f, 0.f, 0.f};

    const int ar = t >> 1, ac0 = (t & 1) * 32;
    const int wn = t & 63, kw0 = (t >> 6) * 16;

    for (int k0 = 0; k0 < K; k0 += 64) {
#pragma unroll
        for (int i = 0; i < 4; ++i) {
            *(v8bf*)&Ash[ar][ac0 + 8 * i] = *(const v8bf*)&Ah[(size_t)(m0 + ar) * K + k0 + ac0 + 8 * i];
            *(v8bf*)&Asl[ar][ac0 + 8 * i] = *(const v8bf*)&Al[(size_t)(m0 + ar) * K + k0 + ac0 + 8 * i];
        }
        {
            const int gn = n0 + wn;
            v8bf h0, l0, h1, l1;
            if (gn < N) {
#pragma unroll
                for (int j = 0; j < 8; ++j) {
                    float w = W[(size_t)(k0 + kw0 + j) * N + gn];
                    h0[j] = (__bf16)w;  l0[j] = (__bf16)(w - (float)h0[j]);
                    float w2 = W[(size_t)(k0 + kw0 + 8 + j) * N + gn];
                    h1[j] = (__bf16)w2; l1[j] = (__bf16)(w2 - (float)h1[j]);
                }
            } else {
#pragma unroll
                for (int j = 0; j < 8; ++j) {
                    h0[j] = (__bf16)0.0f; l0[j] = (__bf16)0.0f;
                    h1[j] = (__bf16)0.0f; l1[j] = (__bf16)0.0f;
                }
            }
            *(v8bf*)&Wsh[wn][kw0]     = h0;  *(v8bf*)&Wsl[wn][kw0]     = l0;
            *(v8bf*)&Wsh[wn][kw0 + 8] = h1;  *(v8bf*)&Wsl[wn][kw0 + 8] = l1;
        }
        __syncthreads();
#pragma unroll
        for (int kk = 0; kk < 2; ++kk) {
            v8bf ah0 = *(const v8bf*)&Ash[wv * 32 + l16][kk * 32 + quad * 8];
            v8bf al0 = *(const v8bf*)&Asl[wv * 32 + l16][kk * 32 + quad * 8];
            v8bf ah1 = *(const v8bf*)&Ash[wv * 32 + 16 + l16][kk * 32 + quad * 8];
            v8bf al1 = *(const v8bf*)&Asl[wv * 32 + 16 + l16][kk * 32 + quad * 8];
#pragma unroll
            for (int ct = 0; ct < 4; ++ct) {
                v8bf bh = *(const v8bf*)&Wsh[ct * 16 + l16][kk * 32 + quad * 8];
                v8bf bl = *(const v8bf*)&Wsl[ct * 16 + l16][kk * 32 + quad * 8];
                acc[0][ct] = __builtin_amdgcn_mfma_f32_16x16x32_bf16(ah0, bh, acc[0][ct], 0, 0, 0);
                acc[0][ct] = __builtin_amdgcn_mfma_f32_16x16x32_bf16(ah0, bl, acc[0][ct], 0, 0, 0);
                acc[0][ct] = __builtin_amdgcn_mfma_f32_16x16x32_bf16(al0, bh, acc[0][ct], 0, 0, 0);
                acc[1][ct] = __builtin_amdgcn_mfma_f32_16x16x32_bf16(ah1, bh, acc[1][ct], 0, 0, 0);
                acc[1][ct] = __builtin_amdgcn_mfma_f32_16x16x32_bf16(ah1, bl, acc[1][ct], 0, 0, 0);
                acc[1][ct] = __builtin_amdgcn_mfma_f32_16x16x32_bf16(al1, bh, acc[1][ct], 0, 0, 0);
            }
        }
        __syncthreads();
    }
#pragma unroll
    for (int rb = 0; rb < 2; ++rb)
#pragma unroll
        for (int ct = 0; ct < 4; ++ct) {
            int gn = n0 + ct * 16 + l16;
            if (gn < N) {
#pragma unroll
                for (int r = 0; r < 4; ++r)
                    C[(size_t)(m0 + wv * 32 + rb * 16 + quad * 4 + r) * N + gn] = acc[rb][ct][r];
            }
        }
}

__global__ __launch_bounds__(256)
void gemm_sp(const __bf16* __restrict__ Ah, const __bf16* __restrict__ Al,
             const float* __restrict__ W, float* __restrict__ C, int N, int K)
{
    gemm_sp_body2(Ah, Al, W, C, N, K, blockIdx.x * 64, blockIdx.y * 128);
}

__global__ __launch_bounds__(256)
void gemm_sp_multi(const __bf16* __restrict__ A0h, const __bf16* __restrict__ A0l,
                   const __bf16* __restrict__ A1h, const __bf16* __restrict__ A1l,
                   int selA, const float* __restrict__ W, float* __restrict__ C)
{
    const int g = blockIdx.x >> 3;
    const int n0 = (blockIdx.x & 7) * 64;
    const int s = (selA >> g) & 1;
    const __bf16* Ah = s ? A1h : A0h;
    const __bf16* Al = s ? A1l : A0l;
    gemm_sp_body2(Ah, Al, W + (size_t)g * EE * EE, C + (size_t)g * (size_t)MM * EE,
                  EE, EE, n0, blockIdx.y * 128);
}

// ======== pre-split GEMM v2: W^T planes staged into LDS (coalesced 16B copies) ========
// Identical to gemm_sp_body2 except the W-stage reads pre-split bf16 W^T directly
// (4 vector loads, no fp32 fetch, no split VALU). LDS layout, barriers, and the MFMA
// loop are byte-identical to the r10-verified body2; staged values identical to the
// r11-verified gemm_ps. Fixes r11's regression: B operands come from LDS again, with
// the staging load acting as the prefetch.
__device__ inline void gemm_ps_body(const __bf16* __restrict__ Ah, const __bf16* __restrict__ Al,
                                    const __bf16* __restrict__ Wth, const __bf16* __restrict__ Wtl,
                                    float* __restrict__ C, int N, int K, int n0, int m0)
{
    __shared__ __bf16 Ash[128][72], Asl[128][72];   // 36.9 KB
    __shared__ __bf16 Wsh[64][72],  Wsl[64][72];    // 18.4 KB
    const int t = threadIdx.x;
    const int wv = t >> 6, lane = t & 63, quad = lane >> 4, l16 = lane & 15;
    v4f acc[2][4];
#pragma unroll
    for (int rb = 0; rb < 2; ++rb)
#pragma unroll
        for (int ct = 0; ct < 4; ++ct) acc[rb][ct] = v4f{0.f, 0.f, 0.f, 0.f};

    const int ar = t >> 1, ac0 = (t & 1) * 32;
    const int wn = t & 63, kw0 = (t >> 6) * 16;

    for (int k0 = 0; k0 < K; k0 += 64) {
#pragma unroll
        for (int i = 0; i < 4; ++i) {
            *(v8bf*)&Ash[ar][ac0 + 8 * i] = *(const v8bf*)&Ah[(size_t)(m0 + ar) * K + k0 + ac0 + 8 * i];
            *(v8bf*)&Asl[ar][ac0 + 8 * i] = *(const v8bf*)&Al[(size_t)(m0 + ar) * K + k0 + ac0 + 8 * i];
        }
        {
            const int gn = n0 + wn;
            v8bf h0, l0, h1, l1;
            if (gn < N) {
                const __bf16* wh = &Wth[(size_t)gn * K + k0 + kw0];
                const __bf16* wl = &Wtl[(size_t)gn * K + k0 + kw0];
                h0 = *(const v8bf*)&wh[0];  h1 = *(const v8bf*)&wh[8];
                l0 = *(const v8bf*)&wl[0];  l1 = *(const v8bf*)&wl[8];
            } else {
#pragma unroll
                for (int j = 0; j < 8; ++j) {
                    h0[j] = (__bf16)0.0f; l0[j] = (__bf16)0.0f;
                    h1[j] = (__bf16)0.0f; l1[j] = (__bf16)0.0f;
                }
            }
            *(v8bf*)&Wsh[wn][kw0]     = h0;  *(v8bf*)&Wsl[wn][kw0]     = l0;
            *(v8bf*)&Wsh[wn][kw0 + 8] = h1;  *(v8bf*)&Wsl[wn][kw0 + 8] = l1;
        }
        __syncthreads();
#pragma unroll
        for (int kk = 0; kk < 2; ++kk) {
            v8bf ah0 = *(const v8bf*)&Ash[wv * 32 + l16][kk * 32 + quad * 8];
            v8bf al0 = *(const v8bf*)&Asl[wv * 32 + l16][kk * 32 + quad * 8];
            v8bf ah1 = *(const v8bf*)&Ash[wv * 32 + 16 + l16][kk * 32 + quad * 8];
            v8bf al1 = *(const v8bf*)&Asl[wv * 32 + 16 + l16][kk * 32 + quad * 8];
#pragma unroll
            for (int ct = 0; ct < 4; ++ct) {
                v8bf bh = *(const v8bf*)&Wsh[ct * 16 + l16][kk * 32 + quad * 8];
                v8bf bl = *(const v8bf*)&Wsl[ct * 16 + l16][kk * 32 + quad * 8];
                acc[0][ct] = __builtin_amdgcn_mfma_f32_16x16x32_bf16(ah0, bh, acc[0][ct], 0, 0, 0);
                acc[0][ct] = __builtin_amdgcn_mfma_f32_16x16x32_bf16(ah0, bl, acc[0][ct], 0, 0, 0);
                acc[0][ct] = __builtin_amdgcn_mfma_f32_16x16x32_bf16(al0, bh, acc[0][ct], 0, 0, 0);
                acc[1][ct] = __builtin_amdgcn_mfma_f32_16x16x32_bf16(ah1, bh, acc[1][ct], 0, 0, 0);
                acc[1][ct] = __builtin_amdgcn_mfma_f32_16x16x32_bf16(ah1, bl, acc[1][ct], 0, 0, 0);
                acc[1][ct] = __builtin_amdgcn_mfma_f32_16x16x32_bf16(al1, bh, acc[1][ct], 0, 0, 0);
            }
        }
        __syncthreads();
    }
#pragma unroll
    for (int rb = 0; rb < 2; ++rb)
#pragma unroll
        for (int ct = 0; ct < 4; ++ct) {
            int gn = n0 + ct * 16 + l16;
            if (gn < N) {
#pragma unroll
                for (int r = 0; r < 4; ++r)
                    C[(size_t)(m0 + wv * 32 + rb * 16 + quad * 4 + r) * N + gn] = acc[rb][ct][r];
            }
        }
}

__global__ __launch_bounds__(256)
void gemm_ps(const __bf16* __restrict__ Ah, const __bf16* __restrict__ Al,
             const __bf16* __restrict__ Wt, float* __restrict__ C, int N, int K)
{
    gemm_ps_body(Ah, Al, Wt, Wt + (size_t)K * N, C, N, K, blockIdx.x * 64, blockIdx.y * 128);
}

__global__ __launch_bounds__(256)
void gemm_ps_multi(const __bf16* __restrict__ A0h, const __bf16* __restrict__ A0l,
                   const __bf16* __restrict__ A1h, const __bf16* __restrict__ A1l,
                   int selA, const __bf16* __restrict__ Wt, float* __restrict__ C)
{
    const int g = blockIdx.x >> 3;
    const int n0 = (blockIdx.x & 7) * 64;
    const int s = (selA >> g) & 1;
    const __bf16* Ah = s ? A1h : A0h;
    const __bf16* Al = s ? A1l : A0l;
    const __bf16* Wth = Wt + (size_t)g * 2 * EE * EE;
    gemm_ps_body(Ah, Al, Wth, Wth + (size_t)EE * EE,
                 C + (size_t)g * (size_t)MM * EE, EE, EE, n0, blockIdx.y * 128);
}

// ===== hybrid retention (round-10 verified PASS config, unchanged) =====
__global__ __launch_bounds__(256)
void ret_hyb2(const float* __restrict__ Q, const float* __restrict__ K,
              const float* __restrict__ V, const float* __restrict__ G,
              const int* __restrict__ seg,
              __bf16* __restrict__ oh, __bf16* __restrict__ ol, int causal)
{
    __shared__ __align__(16) __bf16 Ksh[64][72], Ks1[64][72], Ks2[64][72]; // K planes
    __shared__ __align__(16) float  Vs[64][68];                 // V [m][d] fp32
    __shared__ __align__(16) float  Ps[64][68];                 // P [n][m] fp32
    __shared__ int    segm[64];

    const int t = threadIdx.x;
    const int wv = t >> 6, lane = t & 63, q = lane >> 4, l16 = lane & 15;
    const int nt = blockIdx.x, bh = blockIdx.y;
    const int b = bh >> 3, h = bh & 7;
    const int n0 = nt * 64;
    const size_t base = ((size_t)b * SS) * EE + (size_t)h * DH;
    const float lgg = log2f(1.0f - exp2f(-5.0f - (float)h));

    const int n_a = n0 + wv * 16 + l16;
    v8bf qh[2], q1[2], q2[2];
#pragma unroll
    for (int kk = 0; kk < 2; ++kk) {
        const float* qp = &Q[base + (size_t)n_a * EE + kk * 32 + q * 8];
#pragma unroll
        for (int j = 0; j < 8; ++j) {
            float v = qp[j] * 0.125f;
            __bf16 hh = (__bf16)v;      float r1 = v - (float)hh;
            __bf16 a1 = (__bf16)r1;     float r2 = r1 - (float)a1;
            qh[kk][j] = hh;
            q1[kk][j] = a1;
            q2[kk][j] = (__bf16)r2;
        }
    }
    int nrow[4], sn_[4];
#pragma unroll
    for (int r = 0; r < 4; ++r) {
        nrow[r] = n0 + wv * 16 + q * 4 + r;
        sn_[r] = seg[b * SS + nrow[r]];
    }

    const int rp = t >> 3, dc = (t & 7) * 8;
    float o0[8], o1[8];
#pragma unroll
    for (int j = 0; j < 8; ++j) { o0[j] = 0.f; o1[j] = 0.f; }

    const int mp2 = (t >> 3) * 2;
    const int d0k = (t & 7) * 8;
    const int mr = t >> 2;
    const int c0 = (t & 3) * 16;

    const int mtmax = causal ? nt : (SS / 64 - 1);
    for (int mt = 0; mt <= mtmax; ++mt) {
        const int m0 = mt * 64;
        {
            const float* kp0 = &K[base + (size_t)(m0 + mp2) * EE + d0k];
            float k0[8], k1[8];
            *(float4*)&k0[0] = *(const float4*)&kp0[0];
            *(float4*)&k0[4] = *(const float4*)&kp0[4];
            *(float4*)&k1[0] = *(const float4*)&kp0[EE];
            *(float4*)&k1[4] = *(const float4*)&kp0[EE + 4];
            v8bf kh0, ka0, kb0, kh1, ka1, kb1;
#pragma unroll
            for (int j = 0; j < 8; ++j) {
                __bf16 hh = (__bf16)k0[j];  float r1 = k0[j] - (float)hh;
                __bf16 aa = (__bf16)r1;     float r2 = r1 - (float)aa;
                kh0[j] = hh; ka0[j] = aa; kb0[j] = (__bf16)r2;
                __bf16 hh1 = (__bf16)k1[j]; float s1_ = k1[j] - (float)hh1;
                __bf16 aa1 = (__bf16)s1_;   float s2_ = s1_ - (float)aa1;
                kh1[j] = hh1; ka1[j] = aa1; kb1[j] = (__bf16)s2_;
            }
            *(v8bf*)&Ksh[mp2][d0k]     = kh0;
            *(v8bf*)&Ks1[mp2][d0k]     = ka0;
            *(v8bf*)&Ks2[mp2][d0k]     = kb0;
            *(v8bf*)&Ksh[mp2 + 1][d0k] = kh1;
            *(v8bf*)&Ks1[mp2 + 1][d0k] = ka1;
            *(v8bf*)&Ks2[mp2 + 1][d0k] = kb1;
        }
        {
            const float* vp = &V[base + (size_t)(m0 + mr) * EE + c0];
#pragma unroll
            for (int j = 0; j < 16; j += 4)
                *(float4*)&Vs[mr][c0 + j] = *(const float4*)&vp[j];
        }
        if (t < 64) segm[t] = seg[b * SS + m0 + t];
        __syncthreads();

        v4f sacc[4];
#pragma unroll
        for (int i = 0; i < 4; ++i) sacc[i] = v4f{0.f, 0.f, 0.f, 0.f};
#pragma unroll
        for (int ct = 0; ct < 4; ++ct) {
            const int mrow = ct * 16 + l16;
#pragma unroll
            for (int kk = 0; kk < 2; ++kk) {
                v8bf bh = *(const v8bf*)&Ksh[mrow][kk * 32 + q * 8];
                v8bf b1 = *(const v8bf*)&Ks1[mrow][kk * 32 + q * 8];
                v8bf b2 = *(const v8bf*)&Ks2[mrow][kk * 32 + q * 8];
                sacc[ct] = __builtin_amdgcn_mfma_f32_16x16x32_bf16(qh[kk], bh, sacc[ct], 0, 0, 0);
                sacc[ct] = __builtin_amdgcn_mfma_f32_16x16x32_bf16(qh[kk], b1, sacc[ct], 0, 0, 0);
                sacc[ct] = __builtin_amdgcn_mfma_f32_16x16x32_bf16(q1[kk], bh, sacc[ct], 0, 0, 0);
                sacc[ct] = __builtin_amdgcn_mfma_f32_16x16x32_bf16(q1[kk], b1, sacc[ct], 0, 0, 0);
                sacc[ct] = __builtin_amdgcn_mfma_f32_16x16x32_bf16(qh[kk], b2, sacc[ct], 0, 0, 0);
                sacc[ct] = __builtin_amdgcn_mfma_f32_16x16x32_bf16(q2[kk], bh, sacc[ct], 0, 0, 0);
            }
        }

#pragma unroll
        for (int ct = 0; ct < 4; ++ct) {
            const int m_g = m0 + ct * 16 + l16;
            const int sm = segm[ct * 16 + l16];
#pragma unroll
            for (int r = 0; r < 4; ++r) {
                const int delta = nrow[r] - m_g;
                float f = 0.0f;
                if (sm == sn_[r]) {
                    if (causal) f = (delta >= 0) ? exp2f(lgg * (float)delta) : 0.0f;
                    else        f = exp2f(lgg * fabsf((float)delta));
                }
                Ps[wv * 16 + q * 4 + r][ct * 16 + l16] = sacc[ct][r] * f;
            }
        }
        __syncthreads();

        for (int m = 0; m < 64; m += 4) {
            float4 pa = *(const float4*)&Ps[2 * rp][m];
            float4 pb = *(const float4*)&Ps[2 * rp + 1][m];
#pragma unroll
            for (int j = 0; j < 8; ++j) {
                float v0 = Vs[m + 0][dc + j];
                float v1 = Vs[m + 1][dc + j];
                float v2 = Vs[m + 2][dc + j];
                float v3 = Vs[m + 3][dc + j];
                float a0 = o0[j];
                a0 += pa.x * v0; a0 += pa.y * v1; a0 += pa.z * v2; a0 += pa.w * v3;
                o0[j] = a0;
                float a1 = o1[j];
                a1 += pb.x * v0; a1 += pb.y * v1; a1 += pb.z * v2; a1 += pb.w * v3;
                o1[j] = a1;
            }
        }
        __syncthreads();
    }

    float s10 = 0.f, s20 = 0.f, s11 = 0.f, s21 = 0.f;
#pragma unroll
    for (int j = 0; j < 8; ++j) {
        s10 += o0[j]; s20 += o0[j] * o0[j];
        s11 += o1[j]; s21 += o1[j] * o1[j];
    }
#pragma unroll
    for (int mk = 1; mk < 8; mk <<= 1) {
        s10 += __shfl_xor(s10, mk); s20 += __shfl_xor(s20, mk);
        s11 += __shfl_xor(s11, mk); s21 += __shfl_xor(s21, mk);
    }
    const float mu0 = s10 * (1.0f / 64.0f);
    const float var0 = s20 * (1.0f / 64.0f) - mu0 * mu0;
    const float rstd0 = rsqrtf(var0 + 1e-6f);
    const float mu1 = s11 * (1.0f / 64.0f);
    const float var1 = s21 * (1.0f / 64.0f) - mu1 * mu1;
    const float rstd1 = rsqrtf(var1 + 1e-6f);

    const size_t ob = base + (size_t)(n0 + 2 * rp) * EE + dc;
    const float* gp0 = &G[ob];
    v8bf h0v, l0v, h1v, l1v;
#pragma unroll
    for (int j = 0; j < 8; ++j) {
        float y0 = (o0[j] - mu0) * rstd0;
        float w0 = silu_f(gp0[j]) * y0;
        __bf16 hh0 = (__bf16)w0; h0v[j] = hh0; l0v[j] = (__bf16)(w0 - (float)hh0);
        float y1 = (o1[j] - mu1) * rstd1;
        float w1 = silu_f(gp0[EE + j]) * y1;
        __bf16 hh1 = (__bf16)w1; h1v[j] = hh1; l1v[j] = (__bf16)(w1 - (float)hh1);
    }
    *(v8bf*)&oh[ob] = h0v;      *(v8bf*)&ol[ob] = l0v;
    *(v8bf*)&oh[ob + EE] = h1v; *(v8bf*)&ol[ob + EE] = l1v;
}

// ---------------- rms_fast: fp32 out + bf16 hi/lo planes (verified) ----------------
__global__ __launch_bounds__(256)
void rms_fast(const float* __restrict__ A, const float* __restrict__ Bv,
              const float* __restrict__ scale, float* __restrict__ out,
              __bf16* __restrict__ oh, __bf16* __restrict__ ol, int mode)
{
    int row = blockIdx.x, t = threadIdx.x;
    __shared__ float red[4];
    size_t base = (size_t)row * EE;
    float v0 = A[base + t], v1 = A[base + t + 256];
    if (mode == 1) { v0 += Bv[base + t]; v1 += Bv[base + t + 256]; }
    else if (mode == 2) { v0 = gelu_f(v0); v1 = gelu_f(v1); }
    float ss = v0 * v0 + v1 * v1;
#pragma unroll
    for (int mk = 32; mk; mk >>= 1) ss += __shfl_xor(ss, mk);
    if ((t & 63) == 0) red[t >> 6] = ss;
    __syncthreads();
    float tot = red[0] + red[1] + red[2] + red[3];
    float r = rsqrtf(tot * (1.0f / 512.0f) + 1e-6f);
    float o0 = v0 * r * scale[t];
    float o1 = v1 * r * scale[t + 256];
    out[base + t] = o0;
    out[base + t + 256] = o1;
    __bf16 h0 = (__bf16)o0, h1 = (__bf16)o1;
    oh[base + t] = h0;        ol[base + t] = (__bf16)(o0 - (float)h0);
    oh[base + t + 256] = h1;  ol[base + t + 256] = (__bf16)(o1 - (float)h1);
}

__global__ __launch_bounds__(256)
void smul_planes(const float* __restrict__ A, const float* __restrict__ Bv,
                 __bf16* __restrict__ oh, __bf16* __restrict__ ol)
{
    int i = blockIdx.x * 256 + threadIdx.x;
    float v = silu_f(A[i]) * Bv[i];
    __bf16 h = (__bf16)v;
    oh[i] = h;
    ol[i] = (__bf16)(v - (float)h);
}

__global__ __launch_bounds__(256)
void gather_dumb(const int* __restrict__ action, const float* __restrict__ act_w,
                 float* __restrict__ out)
{
    int idx = blockIdx.x * 256 + threadIdx.x;
    int row = idx >> 9, e = idx & 511;
    int b = row >> 9, s = row & 511;
    int id = (s % NAq == 0) ? 0 : (action[b * SS + s - 1] + 1);
    out[(size_t)row * EE + e] = act_w[(size_t)id * EE + e];
}

extern "C" void kernel_launch(void* const* d_in, const int* in_sizes, int n_in,
                              void* d_out, int out_size, void* d_ws, size_t ws_size,
                              hipStream_t stream)
{
    (void)in_sizes; (void)n_in; (void)out_size;
    const float* obs      = (const float*)d_in[0];
    const int*   action   = (const int*)d_in[1];
    const int*   dones    = (const int*)d_in[3];
    const float* obs_w    = (const float*)d_in[4];
    const float* enc_ln0  = (const float*)d_in[5];
    const float* enc_ret  = (const float*)d_in[6];
    const float* enc_ln   = (const float*)d_in[7];
    const float* enc_ffn  = (const float*)d_in[8];
    const float* act_w    = (const float*)d_in[9];
    const float* dec_ln0  = (const float*)d_in[10];
    const float* dec_ret1 = (const float*)d_in[11];
    const float* dec_ret2 = (const float*)d_in[12];
    const float* dec_ln   = (const float*)d_in[13];
    const float* dec_ffn  = (const float*)d_in[14];
    const float* head_w1  = (const float*)d_in[15];
    const float* head_ln  = (const float*)d_in[16];
    const float* head_w2  = (const float*)d_in[17];
    float* out = (float*)d_out;

    float* ws = (float*)d_ws;
    const size_t SZ = (size_t)MM * EE;
    const size_t EE2 = (size_t)EE * EE;
    const size_t M2 = 2 * EE2;          // per-matrix packed W^T stride (bf16)
    int* seg  = (int*)ws;
    float* fb = ws + 8192;
    float *x  = fb + 0 * SZ, *y  = fb + 1 * SZ, *y2 = fb + 2 * SZ;
    float *Qf = fb + 3 * SZ, *Kf = fb + 4 * SZ, *Vf = fb + 5 * SZ;
    float *Gb = fb + 6 * SZ, *Tb = fb + 7 * SZ, *Ob = fb + 8 * SZ;
    float *QKVG = Qf;
    float *FFN2 = Gb;
    __bf16* bp = (__bf16*)(fb + 9 * SZ);
    __bf16 *xh = bp + 0 * SZ, *xl = bp + 1 * SZ;
    __bf16 *yh = bp + 2 * SZ, *yl = bp + 3 * SZ;
    __bf16 *sh = bp + 4 * SZ, *sl = bp + 5 * SZ;
    __bf16 *obsh = bp + 6 * SZ, *obsl = obsh + (size_t)MM * OBSD;

    // ---- pre-split W^T plane region (after obs planes) ----
    __bf16* wt          = obsl + (size_t)MM * OBSD;
    __bf16* wt_enc_ret  = wt;
    __bf16* wt_enc_ffn  = wt_enc_ret  + 10 * M2;
    __bf16* wt_dec_ret1 = wt_enc_ffn  + 6  * M2;
    __bf16* wt_dec_ret2 = wt_dec_ret1 + 10 * M2;
    __bf16* wt_dec_ffn  = wt_dec_ret2 + 10 * M2;
    __bf16* wt_head1    = wt_dec_ffn  + 6  * M2;
    __bf16* wt_obs      = wt_head1    + M2;
    __bf16* wt_head2    = wt_obs      + 2 * (size_t)OBSD * EE;
    __bf16* wt_end      = wt_head2    + 2 * (size_t)EE * AA;
    const size_t need = (size_t)((const char*)wt_end - (const char*)ws);
    const bool pre = (ws_size >= need);

    dim3 blk(256);

    seg_kernel<<<dim3(1), dim3(64), 0, stream>>>(dones, seg);
    split_kernel<<<dim3(MM * OBSD / 256), blk, 0, stream>>>(obs, obsh, obsl, MM * OBSD);

    if (pre) {
        wsplit_t<<<dim3(8, 8, 10), blk, 0, stream>>>(enc_ret,  wt_enc_ret,  EE, EE);
        wsplit_t<<<dim3(8, 8, 6),  blk, 0, stream>>>(enc_ffn,  wt_enc_ffn,  EE, EE);
        wsplit_t<<<dim3(8, 8, 10), blk, 0, stream>>>(dec_ret1, wt_dec_ret1, EE, EE);
        wsplit_t<<<dim3(8, 8, 10), blk, 0, stream>>>(dec_ret2, wt_dec_ret2, EE, EE);
        wsplit_t<<<dim3(8, 8, 6),  blk, 0, stream>>>(dec_ffn,  wt_dec_ffn,  EE, EE);
        wsplit_t<<<dim3(8, 8, 1),  blk, 0, stream>>>(head_w1,  wt_head1,    EE, EE);
        wsplit_t<<<dim3(8, 2, 1),  blk, 0, stream>>>(obs_w,    wt_obs,      OBSD, EE);
        wsplit_t<<<dim3(1, 8, 1),  blk, 0, stream>>>(head_w2,  wt_head2,    EE, AA);
    }

    auto gemmF = [&](const __bf16* Ah, const __bf16* Al, const float* W, const __bf16* Wt,
                     float* C, int N, int K) {
        if (pre) gemm_ps<<<dim3((N + 63) / 64, MM / 128), blk, 0, stream>>>(Ah, Al, Wt, C, N, K);
        else     gemm_sp<<<dim3((N + 63) / 64, MM / 128), blk, 0, stream>>>(Ah, Al, W, C, N, K);
    };
    auto gemmM = [&](const __bf16* A0h_, const __bf16* A0l_,
                     const __bf16* A1h_, const __bf16* A1l_, int selA,
                     const float* W, const __bf16* Wt, float* C, int ng) {
        if (pre) gemm_ps_multi<<<dim3(8 * ng, MM / 128), blk, 0, stream>>>(A0h_, A0l_, A1h_, A1l_, selA, Wt, C);
        else     gemm_sp_multi<<<dim3(8 * ng, MM / 128), blk, 0, stream>>>(A0h_, A0l_, A1h_, A1l_, selA, W, C);
    };
    auto rms = [&](const float* A, const float* Bv, const float* sc,
                   float* o, __bf16* oh, __bf16* ol, int mode) {
        rms_fast<<<dim3(MM), blk, 0, stream>>>(A, Bv, sc, o, oh, ol, mode);
    };
    auto smul = [&](const float* A, const float* Bv, __bf16* oh, __bf16* ol) {
        smul_planes<<<dim3((int)(SZ / 256)), blk, 0, stream>>>(A, Bv, oh, ol);
    };
    auto attn = [&](int causal) {
        ret_hyb2<<<dim3(SS / 64, BB * HH), blk, 0, stream>>>(Qf, Kf, Vf, Gb, seg, sh, sl, causal);
    };

    // ---- encoder ----
    gemmF(obsh, obsl, obs_w, wt_obs, Ob, EE, OBSD);
    rms(Ob, nullptr, enc_ln0, x, xh, xl, 2);
    for (int i = 0; i < 2; ++i) {
        const float* r = enc_ret + (size_t)i * 5 * EE2;
        const __bf16* rt = wt_enc_ret + (size_t)i * 5 * M2;
        gemmM(xh, xl, xh, xl, 0, r, rt, QKVG, 4);     // Q,K,V,G <- x
        attn(0);                                      // full D_f -> sh/sl (gated)
        gemmF(sh, sl, r + 4 * EE2, rt + 4 * M2, Ob, EE, EE);
        rms(x, Ob, enc_ln + (size_t)(i * 2 + 0) * EE, x, xh, xl, 1);
        const float* f = enc_ffn + (size_t)i * 3 * EE2;
        const __bf16* ft = wt_enc_ffn + (size_t)i * 3 * M2;
        gemmM(xh, xl, xh, xl, 0, f, ft, FFN2, 2);     // gate,up <- x  (Gb,Tb)
        smul(Gb, Tb, sh, sl);
        gemmF(sh, sl, f + 2 * EE2, ft + 2 * M2, Ob, EE, EE);
        rms(x, Ob, enc_ln + (size_t)(i * 2 + 1) * EE, x, xh, xl, 1);
    }

    // ---- decoder ----
    gather_dumb<<<dim3((int)(SZ / 256)), blk, 0, stream>>>(action, act_w, Ob);
    rms(Ob, nullptr, dec_ln0, y, yh, yl, 2);
    for (int i = 0; i < 2; ++i) {
        const float* r1 = dec_ret1 + (size_t)i * 5 * EE2;
        const __bf16* r1t = wt_dec_ret1 + (size_t)i * 5 * M2;
        gemmM(yh, yl, yh, yl, 0, r1, r1t, QKVG, 4);   // all <- y
        attn(1);                                      // causal D_c -> sh/sl (gated)
        gemmF(sh, sl, r1 + 4 * EE2, r1t + 4 * M2, Ob, EE, EE);
        rms(y, Ob, dec_ln + (size_t)(i * 3 + 0) * EE, y, yh, yl, 1);

        const float* r2 = dec_ret2 + (size_t)i * 5 * EE2;
        const __bf16* r2t = wt_dec_ret2 + (size_t)i * 5 * M2;
        gemmM(xh, xl, yh, yl, 0b0110, r2, r2t, QKVG, 4);  // Q<-x, K<-y, V<-y, G<-x
        attn(1);
        gemmF(sh, sl, r2 + 4 * EE2, r2t + 4 * M2, Ob, EE, EE);
        rms(x, Ob, dec_ln + (size_t)(i * 3 + 1) * EE, y2, sh, sl, 1);   // y2 planes = sh/sl

        const float* f = dec_ffn + (size_t)i * 3 * EE2;
        const __bf16* ft = wt_dec_ffn + (size_t)i * 3 * M2;
        gemmM(sh, sl, sh, sl, 0, f, ft, FFN2, 2);     // gate,up <- y2
        smul(Gb, Tb, sh, sl);
        gemmF(sh, sl, f + 2 * EE2, ft + 2 * M2, Ob, EE, EE);
        rms(y2, Ob, dec_ln + (size_t)(i * 3 + 2) * EE, y, yh, yl, 1);
    }

    // ---- head ----
    gemmF(yh, yl, head_w1, wt_head1, Ob, EE, EE);
    rms(Ob, nullptr, head_ln, Tb, sh, sl, 2);
    gemmF(sh, sl, head_w2, wt_head2, out, AA, EE);
}

// Round 16
// 1166.047 us; speedup vs baseline: 1.5480x; 1.0964x over previous
//
#include <hip/hip_runtime.h>
#include <hip/hip_bf16.h>
#include <math.h>

// ---- problem constants ----
#define BB 8
#define SS 512
#define EE 512
#define HH 8
#define DH 64
#define AA 32
#define OBSD 128
#define NAq 8
#define MM (BB*SS)   // 4096 token rows

typedef __bf16 v8bf __attribute__((ext_vector_type(8)));
typedef float  v4f  __attribute__((ext_vector_type(4)));

__device__ inline float gelu_f(float x) {
    float x3 = x * x * x;
    return 0.5f * x * (1.0f + tanhf(0.7978845608028654f * (x + 0.044715f * x3)));
}
__device__ inline float silu_f(float x) { return x / (1.0f + expf(-x)); }

// ---------------- seg (verified) ----------------
__global__ void seg_kernel(const int* __restrict__ dones, int* __restrict__ seg)
{
    int b = threadIdx.x;
    if (b < BB) {
        int acc = 0;
        for (int s = 0; s < SS; ++s) {
            seg[b * SS + s] = acc;
            acc += (dones[b * SS + s] != 0) ? 1 : 0;
        }
    }
}

// ---------------- fp32 -> bf16 hi/lo planes ----------------
__global__ __launch_bounds__(256)
void split_kernel(const float* __restrict__ in, __bf16* __restrict__ h,
                  __bf16* __restrict__ l, int n)
{
    int i = blockIdx.x * 256 + threadIdx.x;
    if (i < n) {
        float v = in[i];
        __bf16 hh = (__bf16)v;
        h[i] = hh;
        l[i] = (__bf16)(v - (float)hh);
    }
}

// ======== split-bf16 MFMA GEMM, v2 geometry (round-10 verified, unchanged) ========
__device__ inline void gemm_sp_body2(const __bf16* __restrict__ Ah, const __bf16* __restrict__ Al,
                                     const float* __restrict__ W, float* __restrict__ C,
                                     int N, int K, int n0, int m0)
{
    __shared__ __bf16 Ash[128][72], Asl[128][72];   // 36.9 KB
    __shared__ __bf16 Wsh[64][72],  Wsl[64][72];    // 18.4 KB
    const int t = threadIdx.x;
    const int wv = t >> 6, lane = t & 63, quad = lane >> 4, l16 = lane & 15;
    v4f acc[2][4];
#pragma unroll
    for (int rb = 0; rb < 2; ++rb)
#pragma unroll
        for (int ct = 0; ct < 4; ++ct) acc[rb][ct] = v4f{0.f, 0.f, 0.f, 0.f};

    const int ar = t >> 1, ac0 = (t & 1) * 32;      // A staging: 2 threads/row, 32 cols each
    const int wn = t & 63, kw0 = (t >> 6) * 16;     // W staging: 1 col/thread, 16 k's

    for (int k0 = 0; k0 < K; k0 += 64) {
#pragma unroll
        for (int i = 0; i < 4; ++i) {
            *(v8bf*)&Ash[ar][ac0 + 8 * i] = *(const v8bf*)&Ah[(size_t)(m0 + ar) * K + k0 + ac0 + 8 * i];
            *(v8bf*)&Asl[ar][ac0 + 8 * i] = *(const v8bf*)&Al[(size_t)(m0 + ar) * K + k0 + ac0 + 8 * i];
        }
        {
            const int gn = n0 + wn;
            v8bf h0, l0, h1, l1;
            if (gn < N) {
#pragma unroll
                for (int j = 0; j < 8; ++j) {
                    float w = W[(size_t)(k0 + kw0 + j) * N + gn];
                    h0[j] = (__bf16)w;  l0[j] = (__bf16)(w - (float)h0[j]);
                    float w2 = W[(size_t)(k0 + kw0 + 8 + j) * N + gn];
                    h1[j] = (__bf16)w2; l1[j] = (__bf16)(w2 - (float)h1[j]);
                }
            } else {
#pragma unroll
                for (int j = 0; j < 8; ++j) {
                    h0[j] = (__bf16)0.0f; l0[j] = (__bf16)0.0f;
                    h1[j] = (__bf16)0.0f; l1[j] = (__bf16)0.0f;
                }
            }
            *(v8bf*)&Wsh[wn][kw0]     = h0;  *(v8bf*)&Wsl[wn][kw0]     = l0;
            *(v8bf*)&Wsh[wn][kw0 + 8] = h1;  *(v8bf*)&Wsl[wn][kw0 + 8] = l1;
        }
        __syncthreads();
#pragma unroll
        for (int kk = 0; kk < 2; ++kk) {
            v8bf ah0 = *(const v8bf*)&Ash[wv * 32 + l16][kk * 32 + quad * 8];
            v8bf al0 = *(const v8bf*)&Asl[wv * 32 + l16][kk * 32 + quad * 8];
            v8bf ah1 = *(const v8bf*)&Ash[wv * 32 + 16 + l16][kk * 32 + quad * 8];
            v8bf al1 = *(const v8bf*)&Asl[wv * 32 + 16 + l16][kk * 32 + quad * 8];
#pragma unroll
            for (int ct = 0; ct < 4; ++ct) {
                v8bf bh = *(const v8bf*)&Wsh[ct * 16 + l16][kk * 32 + quad * 8];
                v8bf bl = *(const v8bf*)&Wsl[ct * 16 + l16][kk * 32 + quad * 8];
                acc[0][ct] = __builtin_amdgcn_mfma_f32_16x16x32_bf16(ah0, bh, acc[0][ct], 0, 0, 0);
                acc[0][ct] = __builtin_amdgcn_mfma_f32_16x16x32_bf16(ah0, bl, acc[0][ct], 0, 0, 0);
                acc[0][ct] = __builtin_amdgcn_mfma_f32_16x16x32_bf16(al0, bh, acc[0][ct], 0, 0, 0);
                acc[1][ct] = __builtin_amdgcn_mfma_f32_16x16x32_bf16(ah1, bh, acc[1][ct], 0, 0, 0);
                acc[1][ct] = __builtin_amdgcn_mfma_f32_16x16x32_bf16(ah1, bl, acc[1][ct], 0, 0, 0);
                acc[1][ct] = __builtin_amdgcn_mfma_f32_16x16x32_bf16(al1, bh, acc[1][ct], 0, 0, 0);
            }
        }
        __syncthreads();
    }
#pragma unroll
    for (int rb = 0; rb < 2; ++rb)
#pragma unroll
        for (int ct = 0; ct < 4; ++ct) {
            int gn = n0 + ct * 16 + l16;
            if (gn < N) {
#pragma unroll
                for (int r = 0; r < 4; ++r)
                    C[(size_t)(m0 + wv * 32 + rb * 16 + quad * 4 + r) * N + gn] = acc[rb][ct][r];
            }
        }
}

__global__ __launch_bounds__(256)
void gemm_sp(const __bf16* __restrict__ Ah, const __bf16* __restrict__ Al,
             const float* __restrict__ W, float* __restrict__ C, int N, int K)
{
    gemm_sp_body2(Ah, Al, W, C, N, K, blockIdx.x * 64, blockIdx.y * 128);
}

__global__ __launch_bounds__(256)
void gemm_sp_multi(const __bf16* __restrict__ A0h, const __bf16* __restrict__ A0l,
                   const __bf16* __restrict__ A1h, const __bf16* __restrict__ A1l,
                   int selA, const float* __restrict__ W, float* __restrict__ C)
{
    const int g = blockIdx.x >> 3;
    const int n0 = (blockIdx.x & 7) * 64;
    const int s = (selA >> g) & 1;
    const __bf16* Ah = s ? A1h : A0h;
    const __bf16* Al = s ? A1l : A0l;
    gemm_sp_body2(Ah, Al, W + (size_t)g * EE * EE, C + (size_t)g * (size_t)MM * EE,
                  EE, EE, n0, blockIdx.y * 128);
}

// ===== hybrid retention (round-10 verified PASS math) + causal load-balance swizzle =====
// Only change vs r10: the block->q-tile mapping. Grid (8,64) at 2 blocks/CU pairs
// blocks (x,y) and (x,y+32) on one CU (256 = 0 mod 8) -> same nt -> causal tail CUs
// run 8+8 m-tiles while head CUs run 1+1. Swizzle nt = (bh&32) ? 7-x : x makes each
// pair complementary (sum 9 tiles). Pure block relabeling: per-(nt,bh) math, outputs,
// and the FP DAG are untouched.
__global__ __launch_bounds__(256)
void ret_hyb2(const float* __restrict__ Q, const float* __restrict__ K,
              const float* __restrict__ V, const float* __restrict__ G,
              const int* __restrict__ seg,
              __bf16* __restrict__ oh, __bf16* __restrict__ ol, int causal)
{
    __shared__ __align__(16) __bf16 Ksh[64][72], Ks1[64][72], Ks2[64][72]; // K planes
    __shared__ __align__(16) float  Vs[64][68];                 // V [m][d] fp32
    __shared__ __align__(16) float  Ps[64][68];                 // P [n][m] fp32
    __shared__ int    segm[64];

    const int t = threadIdx.x;
    const int wv = t >> 6, lane = t & 63, q = lane >> 4, l16 = lane & 15;
    const int xt = blockIdx.x, bh = blockIdx.y;
    const int nt = (bh & 32) ? (SS / 64 - 1 - xt) : xt;   // complementary pairing
    const int b = bh >> 3, h = bh & 7;
    const int n0 = nt * 64;
    const size_t base = ((size_t)b * SS) * EE + (size_t)h * DH;
    const float lgg = log2f(1.0f - exp2f(-5.0f - (float)h));

    const int n_a = n0 + wv * 16 + l16;
    v8bf qh[2], q1[2], q2[2];
#pragma unroll
    for (int kk = 0; kk < 2; ++kk) {
        const float* qp = &Q[base + (size_t)n_a * EE + kk * 32 + q * 8];
#pragma unroll
        for (int j = 0; j < 8; ++j) {
            float v = qp[j] * 0.125f;
            __bf16 hh = (__bf16)v;      float r1 = v - (float)hh;
            __bf16 a1 = (__bf16)r1;     float r2 = r1 - (float)a1;
            qh[kk][j] = hh;
            q1[kk][j] = a1;
            q2[kk][j] = (__bf16)r2;
        }
    }
    int nrow[4], sn_[4];
#pragma unroll
    for (int r = 0; r < 4; ++r) {
        nrow[r] = n0 + wv * 16 + q * 4 + r;
        sn_[r] = seg[b * SS + nrow[r]];
    }

    const int rp = t >> 3, dc = (t & 7) * 8;
    float o0[8], o1[8];
#pragma unroll
    for (int j = 0; j < 8; ++j) { o0[j] = 0.f; o1[j] = 0.f; }

    const int mp2 = (t >> 3) * 2;
    const int d0k = (t & 7) * 8;
    const int mr = t >> 2;
    const int c0 = (t & 3) * 16;

    const int mtmax = causal ? nt : (SS / 64 - 1);
    for (int mt = 0; mt <= mtmax; ++mt) {
        const int m0 = mt * 64;
        {
            const float* kp0 = &K[base + (size_t)(m0 + mp2) * EE + d0k];
            float k0[8], k1[8];
            *(float4*)&k0[0] = *(const float4*)&kp0[0];
            *(float4*)&k0[4] = *(const float4*)&kp0[4];
            *(float4*)&k1[0] = *(const float4*)&kp0[EE];
            *(float4*)&k1[4] = *(const float4*)&kp0[EE + 4];
            v8bf kh0, ka0, kb0, kh1, ka1, kb1;
#pragma unroll
            for (int j = 0; j < 8; ++j) {
                __bf16 hh = (__bf16)k0[j];  float r1 = k0[j] - (float)hh;
                __bf16 aa = (__bf16)r1;     float r2 = r1 - (float)aa;
                kh0[j] = hh; ka0[j] = aa; kb0[j] = (__bf16)r2;
                __bf16 hh1 = (__bf16)k1[j]; float s1_ = k1[j] - (float)hh1;
                __bf16 aa1 = (__bf16)s1_;   float s2_ = s1_ - (float)aa1;
                kh1[j] = hh1; ka1[j] = aa1; kb1[j] = (__bf16)s2_;
            }
            *(v8bf*)&Ksh[mp2][d0k]     = kh0;
            *(v8bf*)&Ks1[mp2][d0k]     = ka0;
            *(v8bf*)&Ks2[mp2][d0k]     = kb0;
            *(v8bf*)&Ksh[mp2 + 1][d0k] = kh1;
            *(v8bf*)&Ks1[mp2 + 1][d0k] = ka1;
            *(v8bf*)&Ks2[mp2 + 1][d0k] = kb1;
        }
        {
            const float* vp = &V[base + (size_t)(m0 + mr) * EE + c0];
#pragma unroll
            for (int j = 0; j < 16; j += 4)
                *(float4*)&Vs[mr][c0 + j] = *(const float4*)&vp[j];
        }
        if (t < 64) segm[t] = seg[b * SS + m0 + t];
        __syncthreads();

        v4f sacc[4];
#pragma unroll
        for (int i = 0; i < 4; ++i) sacc[i] = v4f{0.f, 0.f, 0.f, 0.f};
#pragma unroll
        for (int ct = 0; ct < 4; ++ct) {
            const int mrow = ct * 16 + l16;
#pragma unroll
            for (int kk = 0; kk < 2; ++kk) {
                v8bf bh = *(const v8bf*)&Ksh[mrow][kk * 32 + q * 8];
                v8bf b1 = *(const v8bf*)&Ks1[mrow][kk * 32 + q * 8];
                v8bf b2 = *(const v8bf*)&Ks2[mrow][kk * 32 + q * 8];
                sacc[ct] = __builtin_amdgcn_mfma_f32_16x16x32_bf16(qh[kk], bh, sacc[ct], 0, 0, 0);
                sacc[ct] = __builtin_amdgcn_mfma_f32_16x16x32_bf16(qh[kk], b1, sacc[ct], 0, 0, 0);
                sacc[ct] = __builtin_amdgcn_mfma_f32_16x16x32_bf16(q1[kk], bh, sacc[ct], 0, 0, 0);
                sacc[ct] = __builtin_amdgcn_mfma_f32_16x16x32_bf16(q1[kk], b1, sacc[ct], 0, 0, 0);
                sacc[ct] = __builtin_amdgcn_mfma_f32_16x16x32_bf16(qh[kk], b2, sacc[ct], 0, 0, 0);
                sacc[ct] = __builtin_amdgcn_mfma_f32_16x16x32_bf16(q2[kk], bh, sacc[ct], 0, 0, 0);
            }
        }

#pragma unroll
        for (int ct = 0; ct < 4; ++ct) {
            const int m_g = m0 + ct * 16 + l16;
            const int sm = segm[ct * 16 + l16];
#pragma unroll
            for (int r = 0; r < 4; ++r) {
                const int delta = nrow[r] - m_g;
                float f = 0.0f;
                if (sm == sn_[r]) {
                    if (causal) f = (delta >= 0) ? exp2f(lgg * (float)delta) : 0.0f;
                    else        f = exp2f(lgg * fabsf((float)delta));
                }
                Ps[wv * 16 + q * 4 + r][ct * 16 + l16] = sacc[ct][r] * f;
            }
        }
        __syncthreads();

        for (int m = 0; m < 64; m += 4) {
            float4 pa = *(const float4*)&Ps[2 * rp][m];
            float4 pb = *(const float4*)&Ps[2 * rp + 1][m];
#pragma unroll
            for (int j = 0; j < 8; ++j) {
                float v0 = Vs[m + 0][dc + j];
                float v1 = Vs[m + 1][dc + j];
                float v2 = Vs[m + 2][dc + j];
                float v3 = Vs[m + 3][dc + j];
                float a0 = o0[j];
                a0 += pa.x * v0; a0 += pa.y * v1; a0 += pa.z * v2; a0 += pa.w * v3;
                o0[j] = a0;
                float a1 = o1[j];
                a1 += pb.x * v0; a1 += pb.y * v1; a1 += pb.z * v2; a1 += pb.w * v3;
                o1[j] = a1;
            }
        }
        __syncthreads();
    }

    float s10 = 0.f, s20 = 0.f, s11 = 0.f, s21 = 0.f;
#pragma unroll
    for (int j = 0; j < 8; ++j) {
        s10 += o0[j]; s20 += o0[j] * o0[j];
        s11 += o1[j]; s21 += o1[j] * o1[j];
    }
#pragma unroll
    for (int mk = 1; mk < 8; mk <<= 1) {
        s10 += __shfl_xor(s10, mk); s20 += __shfl_xor(s20, mk);
        s11 += __shfl_xor(s11, mk); s21 += __shfl_xor(s21, mk);
    }
    const float mu0 = s10 * (1.0f / 64.0f);
    const float var0 = s20 * (1.0f / 64.0f) - mu0 * mu0;
    const float rstd0 = rsqrtf(var0 + 1e-6f);
    const float mu1 = s11 * (1.0f / 64.0f);
    const float var1 = s21 * (1.0f / 64.0f) - mu1 * mu1;
    const float rstd1 = rsqrtf(var1 + 1e-6f);

    const size_t ob = base + (size_t)(n0 + 2 * rp) * EE + dc;
    const float* gp0 = &G[ob];
    v8bf h0v, l0v, h1v, l1v;
#pragma unroll
    for (int j = 0; j < 8; ++j) {
        float y0 = (o0[j] - mu0) * rstd0;
        float w0 = silu_f(gp0[j]) * y0;
        __bf16 hh0 = (__bf16)w0; h0v[j] = hh0; l0v[j] = (__bf16)(w0 - (float)hh0);
        float y1 = (o1[j] - mu1) * rstd1;
        float w1 = silu_f(gp0[EE + j]) * y1;
        __bf16 hh1 = (__bf16)w1; h1v[j] = hh1; l1v[j] = (__bf16)(w1 - (float)hh1);
    }
    *(v8bf*)&oh[ob] = h0v;      *(v8bf*)&ol[ob] = l0v;
    *(v8bf*)&oh[ob + EE] = h1v; *(v8bf*)&ol[ob + EE] = l1v;
}

// ---------------- rms_fast: fp32 out + bf16 hi/lo planes (verified) ----------------
__global__ __launch_bounds__(256)
void rms_fast(const float* __restrict__ A, const float* __restrict__ Bv,
              const float* __restrict__ scale, float* __restrict__ out,
              __bf16* __restrict__ oh, __bf16* __restrict__ ol, int mode)
{
    int row = blockIdx.x, t = threadIdx.x;
    __shared__ float red[4];
    size_t base = (size_t)row * EE;
    float v0 = A[base + t], v1 = A[base + t + 256];
    if (mode == 1) { v0 += Bv[base + t]; v1 += Bv[base + t + 256]; }
    else if (mode == 2) { v0 = gelu_f(v0); v1 = gelu_f(v1); }
    float ss = v0 * v0 + v1 * v1;
#pragma unroll
    for (int mk = 32; mk; mk >>= 1) ss += __shfl_xor(ss, mk);
    if ((t & 63) == 0) red[t >> 6] = ss;
    __syncthreads();
    float tot = red[0] + red[1] + red[2] + red[3];
    float r = rsqrtf(tot * (1.0f / 512.0f) + 1e-6f);
    float o0 = v0 * r * scale[t];
    float o1 = v1 * r * scale[t + 256];
    out[base + t] = o0;
    out[base + t + 256] = o1;
    __bf16 h0 = (__bf16)o0, h1 = (__bf16)o1;
    oh[base + t] = h0;        ol[base + t] = (__bf16)(o0 - (float)h0);
    oh[base + t + 256] = h1;  ol[base + t + 256] = (__bf16)(o1 - (float)h1);
}

__global__ __launch_bounds__(256)
void smul_planes(const float* __restrict__ A, const float* __restrict__ Bv,
                 __bf16* __restrict__ oh, __bf16* __restrict__ ol)
{
    int i = blockIdx.x * 256 + threadIdx.x;
    float v = silu_f(A[i]) * Bv[i];
    __bf16 h = (__bf16)v;
    oh[i] = h;
    ol[i] = (__bf16)(v - (float)h);
}

__global__ __launch_bounds__(256)
void gather_dumb(const int* __restrict__ action, const float* __restrict__ act_w,
                 float* __restrict__ out)
{
    int idx = blockIdx.x * 256 + threadIdx.x;
    int row = idx >> 9, e = idx & 511;
    int b = row >> 9, s = row & 511;
    int id = (s % NAq == 0) ? 0 : (action[b * SS + s - 1] + 1);
    out[(size_t)row * EE + e] = act_w[(size_t)id * EE + e];
}

extern "C" void kernel_launch(void* const* d_in, const int* in_sizes, int n_in,
                              void* d_out, int out_size, void* d_ws, size_t ws_size,
                              hipStream_t stream)
{
    (void)in_sizes; (void)n_in; (void)out_size; (void)ws_size;
    const float* obs      = (const float*)d_in[0];
    const int*   action   = (const int*)d_in[1];
    const int*   dones    = (const int*)d_in[3];
    const float* obs_w    = (const float*)d_in[4];
    const float* enc_ln0  = (const float*)d_in[5];
    const float* enc_ret  = (const float*)d_in[6];
    const float* enc_ln   = (const float*)d_in[7];
    const float* enc_ffn  = (const float*)d_in[8];
    const float* act_w    = (const float*)d_in[9];
    const float* dec_ln0  = (const float*)d_in[10];
    const float* dec_ret1 = (const float*)d_in[11];
    const float* dec_ret2 = (const float*)d_in[12];
    const float* dec_ln   = (const float*)d_in[13];
    const float* dec_ffn  = (const float*)d_in[14];
    const float* head_w1  = (const float*)d_in[15];
    const float* head_ln  = (const float*)d_in[16];
    const float* head_w2  = (const float*)d_in[17];
    float* out = (float*)d_out;

    float* ws = (float*)d_ws;
    const size_t SZ = (size_t)MM * EE;
    int* seg  = (int*)ws;
    float* fb = ws + 8192;
    float *x  = fb + 0 * SZ, *y  = fb + 1 * SZ, *y2 = fb + 2 * SZ;
    float *Qf = fb + 3 * SZ, *Kf = fb + 4 * SZ, *Vf = fb + 5 * SZ;
    float *Gb = fb + 6 * SZ, *Tb = fb + 7 * SZ, *Ob = fb + 8 * SZ;
    float *QKVG = Qf;
    float *FFN2 = Gb;
    __bf16* bp = (__bf16*)(fb + 9 * SZ);
    __bf16 *xh = bp + 0 * SZ, *xl = bp + 1 * SZ;
    __bf16 *yh = bp + 2 * SZ, *yl = bp + 3 * SZ;
    __bf16 *sh = bp + 4 * SZ, *sl = bp + 5 * SZ;
    __bf16 *obsh = bp + 6 * SZ, *obsl = obsh + (size_t)MM * OBSD;

    const size_t EE2 = (size_t)EE * EE;
    dim3 blk(256);

    seg_kernel<<<dim3(1), dim3(64), 0, stream>>>(dones, seg);
    split_kernel<<<dim3(MM * OBSD / 256), blk, 0, stream>>>(obs, obsh, obsl, MM * OBSD);

    auto gemmF = [&](const __bf16* Ah, const __bf16* Al, const float* W, float* C, int N, int K) {
        gemm_sp<<<dim3((N + 63) / 64, MM / 128), blk, 0, stream>>>(Ah, Al, W, C, N, K);
    };
    auto gemmM = [&](const __bf16* A0h_, const __bf16* A0l_,
                     const __bf16* A1h_, const __bf16* A1l_, int selA,
                     const float* W, float* C, int ng) {
        gemm_sp_multi<<<dim3(8 * ng, MM / 128), blk, 0, stream>>>(A0h_, A0l_, A1h_, A1l_, selA, W, C);
    };
    auto rms = [&](const float* A, const float* Bv, const float* sc,
                   float* o, __bf16* oh, __bf16* ol, int mode) {
        rms_fast<<<dim3(MM), blk, 0, stream>>>(A, Bv, sc, o, oh, ol, mode);
    };
    auto smul = [&](const float* A, const float* Bv, __bf16* oh, __bf16* ol) {
        smul_planes<<<dim3((int)(SZ / 256)), blk, 0, stream>>>(A, Bv, oh, ol);
    };
    // fused attention: QK^T+decay+PV+GroupNorm+silu(G)*y -> sh/sl planes
    auto attn = [&](int causal) {
        ret_hyb2<<<dim3(SS / 64, BB * HH), blk, 0, stream>>>(Qf, Kf, Vf, Gb, seg, sh, sl, causal);
    };

    // ---- encoder ----
    gemmF(obsh, obsl, obs_w, Ob, EE, OBSD);
    rms(Ob, nullptr, enc_ln0, x, xh, xl, 2);
    for (int i = 0; i < 2; ++i) {
        const float* r = enc_ret + (size_t)i * 5 * EE2;
        gemmM(xh, xl, xh, xl, 0, r, QKVG, 4);     // Q,K,V,G <- x
        attn(0);                                  // full D_f -> sh/sl (gated)
        gemmF(sh, sl, r + 4 * EE2, Ob, EE, EE);
        rms(x, Ob, enc_ln + (size_t)(i * 2 + 0) * EE, x, xh, xl, 1);
        const float* f = enc_ffn + (size_t)i * 3 * EE2;
        gemmM(xh, xl, xh, xl, 0, f, FFN2, 2);     // gate,up <- x  (Gb,Tb)
        smul(Gb, Tb, sh, sl);
        gemmF(sh, sl, f + 2 * EE2, Ob, EE, EE);
        rms(x, Ob, enc_ln + (size_t)(i * 2 + 1) * EE, x, xh, xl, 1);
    }

    // ---- decoder ----
    gather_dumb<<<dim3((int)(SZ / 256)), blk, 0, stream>>>(action, act_w, Ob);
    rms(Ob, nullptr, dec_ln0, y, yh, yl, 2);
    for (int i = 0; i < 2; ++i) {
        const float* r1 = dec_ret1 + (size_t)i * 5 * EE2;
        gemmM(yh, yl, yh, yl, 0, r1, QKVG, 4);    // all <- y
        attn(1);                                  // causal D_c -> sh/sl (gated)
        gemmF(sh, sl, r1 + 4 * EE2, Ob, EE, EE);
        rms(y, Ob, dec_ln + (size_t)(i * 3 + 0) * EE, y, yh, yl, 1);

        const float* r2 = dec_ret2 + (size_t)i * 5 * EE2;
        gemmM(xh, xl, yh, yl, 0b0110, r2, QKVG, 4);  // Q<-x, K<-y, V<-y, G<-x
        attn(1);
        gemmF(sh, sl, r2 + 4 * EE2, Ob, EE, EE);
        rms(x, Ob, dec_ln + (size_t)(i * 3 + 1) * EE, y2, sh, sl, 1);   // y2 planes = sh/sl

        const float* f = dec_ffn + (size_t)i * 3 * EE2;
        gemmM(sh, sl, sh, sl, 0, f, FFN2, 2);     // gate,up <- y2
        smul(Gb, Tb, sh, sl);
        gemmF(sh, sl, f + 2 * EE2, Ob, EE, EE);
        rms(y2, Ob, dec_ln + (size_t)(i * 3 + 2) * EE, y, yh, yl, 1);
    }

    // ---- head ----
    gemmF(yh, yl, head_w1, Ob, EE, EE);
    rms(Ob, nullptr, head_ln, Tb, sh, sl, 2);
    gemmF(sh, sl, head_w2, out, AA, EE);
}